// Round 8
// baseline (481.654 us; speedup 1.0000x reference)
//
#include <hip/hip_runtime.h>

#define B_ 4
#define T_ 2048
#define C_ 32
#define H_ 4
#define DQK 416
#define DV 512
#define QSCALE 0.049029033784546f   // 1/sqrt(416)
#define LOG2E 1.4426950408889634f
// kf fragment layout: [bh][kt 64][sf 26][hi 2][key 32][8]
#define KF_BH 851968
#define KF_KT 13312      // shorts per kt tile (26*2*32*8)
// vt fragment layout: [bh][kt 64][dt 16][kh 2][grp 2][qll 32][8tok]
#define VT_KT 16384      // shorts per kt tile

typedef __attribute__((ext_vector_type(8))) short short8;
typedef __attribute__((ext_vector_type(4))) short short4_;
typedef __attribute__((ext_vector_type(4))) float float4_;
typedef __attribute__((ext_vector_type(16))) float f32x16;

#define GLOBAL_AS __attribute__((address_space(1)))
#define LDS_AS __attribute__((address_space(3)))

// packed nibble tables (blade j -> value), LSB nibble = j0
#define GRADE_PK 0x4333322222211110ULL
#define E0B_PK   0x8077700066600050ULL
#define SRC_PK   0xE0A9800043200000ULL
#define IPOS_PK  0x0700065400032100ULL
#define E0MASK   0xB8E2
#define INVMASK  0x471D
#define QKMASK   0x7F1D
#define BL_PK    0xEAFD98CB43762051ULL

__device__ __forceinline__ float bf2f(unsigned short u){
  union{unsigned int i; float f;} v; v.i = ((unsigned int)u) << 16; return v.f;
}
__device__ __forceinline__ unsigned short f2bf(float f){
  union{float f; unsigned int i;} v; v.f = f;
  unsigned int x = v.i;
  unsigned int r = x + 0x7FFFu + ((x >> 16) & 1u);
  return (unsigned short)(r >> 16);
}
__device__ __forceinline__ unsigned pkbf(float a, float b){
  unsigned ua = __float_as_uint(a) + 0x8000u;
  unsigned ub = __float_as_uint(b) + 0x8000u;
  return __builtin_amdgcn_perm(ub, ua, 0x07060302u);
}

// ---------------- k0: weight prep ----------------
__global__ void k0_prep(const float* __restrict__ w_qkv, const float* __restrict__ w_out,
                        const float* __restrict__ lnw, const float* __restrict__ mix_ipa,
                        const float* __restrict__ mix_daa,
                        unsigned short* __restrict__ wqb, unsigned short* __restrict__ wob,
                        float* __restrict__ wI, float* __restrict__ wD){
  int idx = blockIdx.x * 256 + threadIdx.x;
  if (idx < 9*384*32){
    int i = idx & 31;
    int rest = idx >> 5;
    int o = rest % 384;
    int bb = rest / 384;
    wqb[idx] = f2bf(w_qkv[(o*32 + i)*9 + bb] * lnw[i]);
  }
  if (idx < 9*32*128){
    int i = idx & 127;
    int rest = idx >> 7;
    int o = rest & 31;
    int bb = rest >> 5;
    wob[idx] = f2bf(w_out[(o*128 + i)*9 + bb]);
  }
  if (idx < 128){
    wI[idx] = __expf(mix_ipa[idx]);
    wD[idx] = __expf(mix_daa[idx]);
  }
}

// ---------------- k1: norm + QKV equi-linear + feature build ----------------
// LDS: xJ 20480 | invr 64 | red 512 | ost 4x13568 = 54272  => 75328B (2 blocks/CU)
__global__ __launch_bounds__(256) void k1_qkv(
    const float* __restrict__ x, const unsigned short* __restrict__ wqb,
    const float* __restrict__ wI, const float* __restrict__ wD,
    unsigned short* __restrict__ qf, unsigned short* __restrict__ kf,
    unsigned short* __restrict__ vt){
  extern __shared__ char smem[];
  unsigned short* xJ = (unsigned short*)smem;
  float* invr = (float*)(smem + 20480);
  float* red  = (float*)(smem + 20544);
  unsigned short* ostage = (unsigned short*)(smem + 21056);

  int tid = threadIdx.x;
  int tile = blockIdx.x;
  int b = tile >> 7;
  int t0 = (tile & 127) << 4;

  const float* xt = x + ((size_t)(b*T_ + t0)) * 512;
  #pragma unroll
  for (int pass = 0; pass < 8; ++pass){
    int g = tid + pass*256;
    int t = g >> 7, r = g & 127;
    int ci = r >> 2, j4 = (r & 3) << 2;
    float4_ v = *(const float4_*)(xt + (size_t)t*512 + ci*16 + j4);
    #pragma unroll
    for (int d = 0; d < 4; ++d){
      xJ[((j4 + d)*16 + t)*40 + ci] = f2bf(v[d]);
    }
  }
  __syncthreads();
  if (tid < 128){
    int t = tid >> 3, p = tid & 7;
    int j = (int)((0xEA984320u >> (p*4)) & 15u);
    float s = 0.f;
    #pragma unroll
    for (int i = 0; i < 32; ++i){
      float v = bf2f(xJ[(j*16 + t)*40 + i]);
      s += v*v;
    }
    red[t*8 + p] = s;
  }
  __syncthreads();
  if (tid < 16){
    float s = 0.f;
    #pragma unroll
    for (int p = 0; p < 8; ++p) s += red[tid*8 + p];
    invr[tid] = rsqrtf(s * (1.0f/32.0f) + 1e-5f);
  }
  __syncthreads();

  int wv = tid >> 6, lane = tid & 63, lm = lane & 15, kg = lane >> 4;
  unsigned short* ost = ostage + wv * 6784;   // 16 x 424 shorts
  int h = wv;
  int bh = b * H_ + h;
  unsigned short* vtb = vt + (size_t)bh * 64 * VT_KT;
  const float QSC2 = QSCALE * LOG2E;

  for (int s = 0; s < 3; ++s){
    int c12 = s*4 + h;
    float pr0[2][4], pr1[2][4], pr2[2][4];
    #pragma unroll
    for (int j = 0; j < 16; ++j){
      if (s < 2 && !((QKMASK >> j) & 1)) continue;
      int g  = (int)((GRADE_PK >> (j*4)) & 15);
      bool e0 = (E0MASK >> j) & 1;
      int eb = (int)((E0B_PK >> (j*4)) & 15);
      int sj = (int)((SRC_PK >> (j*4)) & 15);
      #pragma unroll
      for (int nt = 0; nt < 2; ++nt){
        int o = c12*32 + nt*16 + lm;
        float4_ acc = {0.f, 0.f, 0.f, 0.f};
        short8 a0 = *(const short8*)&xJ[(j*16 + lm)*40 + kg*8];
        short8 b0 = *(const short8*)&wqb[((size_t)(g*384 + o))*32 + kg*8];
        acc = __builtin_amdgcn_mfma_f32_16x16x32_bf16(a0, b0, acc, 0, 0, 0);
        if (e0){
          short8 a1 = *(const short8*)&xJ[(sj*16 + lm)*40 + kg*8];
          short8 b1 = *(const short8*)&wqb[((size_t)(eb*384 + o))*32 + kg*8];
          acc = __builtin_amdgcn_mfma_f32_16x16x32_bf16(a1, b1, acc, 0, 0, 0);
        }
        int c = nt*16 + lm;
        if (s == 2){
          // direct store to vt fragment layout (4 tokens contiguous in the 8-slot)
          int dim = c*16 + j;
          short4_ w;
          #pragma unroll
          for (int r = 0; r < 4; ++r) w[r] = (short)f2bf(acc[r] * invr[kg*4 + r]);
          int dt = dim >> 5, qll = dim & 31;
          size_t off = (size_t)(t0 >> 5)*VT_KT + dt*1024 + ((t0 >> 4) & 1)*512
                     + (kg >> 1)*256 + qll*8 + (kg & 1)*4;
          *(short4_*)(vtb + off) = w;
        } else {
          #pragma unroll
          for (int r = 0; r < 4; ++r){
            int t = kg*4 + r;
            float val = acc[r] * invr[t];
            if ((INVMASK >> j) & 1){
              int p = (int)((IPOS_PK >> (j*4)) & 15);
              float f = (s == 0) ? val * wI[h*32 + c] * QSC2 : val;
              ost[t*424 + c*8 + p] = f2bf(f);
            } else {
              float f = (s == 0) ? val * (2.0f * QSC2) * wD[h*32 + c] : val;
              ost[t*424 + 256 + c*5 + (j - 11)] = f2bf(f);
              if (j == 11) pr0[nt][r] = val;
              else if (j == 12) pr1[nt][r] = val;
              else pr2[nt][r] = val;
            }
          }
        }
      }
    }
    if (s < 2){
      // |p|^2 and const slots from registers (lane-local)
      #pragma unroll
      for (int nt = 0; nt < 2; ++nt){
        int c = nt*16 + lm;
        #pragma unroll
        for (int r = 0; r < 4; ++r){
          int t = kg*4 + r;
          float ps = pr0[nt][r]*pr0[nt][r] + pr1[nt][r]*pr1[nt][r] + pr2[nt][r]*pr2[nt][r];
          if (s == 0){
            float wd = wD[h*32 + c] * QSC2;
            ost[t*424 + 256 + c*5 + 3] = f2bf(-ps * wd);
            ost[t*424 + 256 + c*5 + 4] = f2bf(-wd);
          } else {
            ost[t*424 + 256 + c*5 + 3] = f2bf(1.0f);
            ost[t*424 + 256 + c*5 + 4] = f2bf(ps);
          }
        }
      }
      if (s == 0){
        unsigned short* dst = qf + ((size_t)bh*T_ + t0) * DQK;
        for (int ch = lane; ch < 832; ch += 64){
          int t = ch / 52, c8 = ch % 52;
          *(short8*)(dst + (size_t)t*DQK + c8*8) = *(const short8*)&ost[t*424 + c8*8];
        }
      } else {
        unsigned short* dst = kf + (size_t)bh * KF_BH;
        for (int ch = lane; ch < 832; ch += 64){
          int t = ch / 52, c8 = ch % 52;
          int f0 = c8 * 8;
          int hf2 = (f0 >= 208);
          int fl = f0 - hf2*208;
          int s_ = fl >> 4;
          int hi2 = (fl >> 3) & 1;
          int tt = t0 + t;
          size_t off = ((((size_t)(tt >> 5)*26 + hf2*13 + s_)*2 + hi2)*32 + (tt & 31))*8;
          *(short8*)(dst + off) = *(const short8*)&ost[t*424 + c8*8];
        }
      }
    }
  }
}

// ---------------- k3: flash attention, 32x32 swapped-MFMA, 4-way feat/dim split ----------
// grid 1024 = [chunk desc 64][bhlo 2][xcd 8], block 256 (4 waves), 3 blocks/CU.
// Wave wv: QK feature quarter, PV dim quarter. K: SINGLE LDS buffer, block-cooperative
// global_load_lds staged AFTER B1 (all QK ds_reads drained at the barrier -> overwrite safe;
// staging drains at B2 under merge+softmax+PV). V direct fragment loads issued at iter top.
// LDS: kbuf 26624B | sx 4x[32][36] f32 18432B => 45056B (3 blocks/CU)
__device__ __forceinline__ void stageK2(const unsigned short* src, unsigned short* dst, int tid){
  const char* s = (const char*)src;
  char* d = (char*)dst;
  #pragma unroll
  for (int i = 0; i < 6; ++i)
    __builtin_amdgcn_global_load_lds((const GLOBAL_AS void*)(s + (i*256 + tid)*16),
                                     (LDS_AS void*)(d + (i*256 + tid)*16), 16, 0, 0);
  if (tid < 128)
    __builtin_amdgcn_global_load_lds((const GLOBAL_AS void*)(s + (1536 + tid)*16),
                                     (LDS_AS void*)(d + (1536 + tid)*16), 16, 0, 0);
}

__global__ __launch_bounds__(256, 3) void k3_attn(
    const unsigned short* __restrict__ qf, const unsigned short* __restrict__ kf,
    const unsigned short* __restrict__ vt, unsigned short* __restrict__ O){
  extern __shared__ char smem[];
  unsigned short* kbuf = (unsigned short*)smem;          // 13312 shorts (single buffer)
  float* sx = (float*)(smem + 26624);                    // 4 x 1152 f32
  unsigned short* ostage = (unsigned short*)smem;        // epilogue alias [32][536]

  int tid = threadIdx.x, wv = tid >> 6, lane = tid & 63;
  int ql = lane & 31, hi = lane >> 5;
  int blk = blockIdx.x;
  int bh = 2*(blk & 7) + ((blk >> 3) & 1);
  int chunk = 63 - (blk >> 4);
  int q0 = chunk * 32;

  const unsigned short* qfb = qf + (size_t)bh * T_ * DQK;
  const unsigned short* kfb = kf + (size_t)bh * KF_BH;
  const unsigned short* vtb = vt + (size_t)bh * 64 * VT_KT;
  unsigned short* Ob = O + (size_t)bh * T_ * DV;

  int FS = (wv < 2) ? wv*7 : 14 + (wv - 2)*6;     // sf base
  int FB = (wv < 2) ? wv*112 : 224 + (wv - 2)*96; // feature base

  // Q fragments (6 or 7 per wave)
  short8 qfr[7];
  {
    const unsigned short* qrow = qfb + (size_t)(q0 + ql)*DQK + FB + hi*8;
    #pragma unroll
    for (int s_ = 0; s_ < 6; ++s_) qfr[s_] = *(const short8*)(qrow + s_*16);
    if (wv < 2) qfr[6] = *(const short8*)(qrow + 96);
  }

  f32x16 acc[4];
  #pragma unroll
  for (int i = 0; i < 4; ++i){
    #pragma unroll
    for (int j = 0; j < 16; ++j) acc[i][j] = 0.f;
  }
  float m = -1e30f, l = 0.f;

  // prologue: stage K(0)
  stageK2(kfb, kbuf, tid);
  __syncthreads();

  for (int kt = 0; kt <= chunk; ++kt){
    // V fragment loads: issue early, consumed at PV (latency spans QK+B1+merge+softmax)
    short8 vf[8];
    {
      const unsigned short* vk = vtb + (size_t)kt*VT_KT + (wv*4)*1024 + lane*8;
      #pragma unroll
      for (int dti = 0; dti < 4; ++dti){
        vf[dti*2]     = *(const short8*)(vk + dti*1024);
        vf[dti*2 + 1] = *(const short8*)(vk + dti*1024 + 512);
      }
    }
    // QK quarter from kbuf
    f32x16 S;
    #pragma unroll
    for (int j = 0; j < 16; ++j) S[j] = 0.f;
    __builtin_amdgcn_s_setprio(1);
    #pragma unroll
    for (int s_ = 0; s_ < 6; ++s_){
      short8 kfr = *(const short8*)&kbuf[(FS + s_)*512 + hi*256 + ql*8];
      S = __builtin_amdgcn_mfma_f32_32x32x16_bf16(kfr, qfr[s_], S, 0, 0, 0);
    }
    if (wv < 2){
      short8 kfr = *(const short8*)&kbuf[(FS + 6)*512 + hi*256 + ql*8];
      S = __builtin_amdgcn_mfma_f32_32x32x16_bf16(kfr, qfr[6], S, 0, 0, 0);
    }
    __builtin_amdgcn_s_setprio(0);
    // write own quarter-scores
    {
      float* sxw = sx + wv*1152 + ql*36;
      #pragma unroll
      for (int g = 0; g < 4; ++g){
        float4_ w4;
        #pragma unroll
        for (int u = 0; u < 4; ++u) w4[u] = S[g*4 + u];
        *(float4_*)(sxw + g*8 + hi*4) = w4;
      }
    }
    __syncthreads();   // B1: quarters exchanged; all kbuf ds_reads drained
    // merge 3 partners
    float s_[16];
    {
      int w1 = (wv + 1) & 3, w2 = (wv + 2) & 3, w3 = (wv + 3) & 3;
      #pragma unroll
      for (int g = 0; g < 4; ++g){
        float4_ a1 = *(const float4_*)(sx + w1*1152 + ql*36 + g*8 + hi*4);
        float4_ a2 = *(const float4_*)(sx + w2*1152 + ql*36 + g*8 + hi*4);
        float4_ a3 = *(const float4_*)(sx + w3*1152 + ql*36 + g*8 + hi*4);
        #pragma unroll
        for (int u = 0; u < 4; ++u) s_[g*4 + u] = S[g*4 + u] + a1[u] + a2[u] + a3[u];
      }
    }
    // stage K(kt+1) into the (now-free) single buffer; drains at B2
    if (kt < chunk) stageK2(kfb + (size_t)(kt + 1)*KF_KT, kbuf, tid);
    // causal mask (diagonal tile)
    if (kt == chunk){
      #pragma unroll
      for (int r = 0; r < 16; ++r){
        int kr = (r & 3) + 8*(r >> 2) + 4*hi;
        if (kr > ql) s_[r] = -1e30f;
      }
    }
    // online softmax in exp2 domain
    float mx0 = fmaxf(fmaxf(s_[0], s_[1]), s_[2]);
    float mx1 = fmaxf(fmaxf(s_[3], s_[4]), s_[5]);
    float mx2 = fmaxf(fmaxf(s_[6], s_[7]), s_[8]);
    float mx3 = fmaxf(fmaxf(s_[9], s_[10]), s_[11]);
    float mx4 = fmaxf(fmaxf(s_[12], s_[13]), s_[14]);
    float pmax = fmaxf(fmaxf(fmaxf(mx0, mx1), fmaxf(mx2, mx3)), fmaxf(mx4, s_[15]));
    pmax = fmaxf(pmax, __shfl_xor(pmax, 32));
    if (!__all(pmax <= m + 11.54f)){
      float mn = fmaxf(m, pmax);
      float al = __builtin_amdgcn_exp2f(m - mn);
      m = mn; l *= al;
      #pragma unroll
      for (int dt = 0; dt < 4; ++dt) acc[dt] *= al;
    }
    float p[16]; float rs = 0.f;
    #pragma unroll
    for (int r = 0; r < 16; ++r){ p[r] = __builtin_amdgcn_exp2f(s_[r] - m); rs += p[r]; }
    rs += __shfl_xor(rs, 32);
    l += rs;
    // pack P^T into B-fragments
    unsigned A0 = pkbf(p[0],  p[1]);
    unsigned A1 = pkbf(p[2],  p[3]);
    unsigned A2 = pkbf(p[4],  p[5]);
    unsigned A3 = pkbf(p[6],  p[7]);
    unsigned A4 = pkbf(p[8],  p[9]);
    unsigned A5 = pkbf(p[10], p[11]);
    unsigned A6 = pkbf(p[12], p[13]);
    unsigned A7 = pkbf(p[14], p[15]);
    unsigned S0 = __shfl_xor((int)A0, 32), S2 = __shfl_xor((int)A2, 32);
    unsigned S1 = __shfl_xor((int)A1, 32), S3 = __shfl_xor((int)A3, 32);
    unsigned S4 = __shfl_xor((int)A4, 32), S6 = __shfl_xor((int)A6, 32);
    unsigned S5 = __shfl_xor((int)A5, 32), S7 = __shfl_xor((int)A7, 32);
    union { unsigned u[4]; short8 s8; } P0, P1;
    P0.u[0] = hi ? S2 : A0;  P0.u[1] = hi ? S3 : A1;
    P0.u[2] = hi ? A2 : S0;  P0.u[3] = hi ? A3 : S1;
    P1.u[0] = hi ? S6 : A4;  P1.u[1] = hi ? S7 : A5;
    P1.u[2] = hi ? A6 : S4;  P1.u[3] = hi ? A7 : S5;
    // PV: own 128-dim quarter
    __builtin_amdgcn_s_setprio(1);
    #pragma unroll
    for (int dti = 0; dti < 4; ++dti){
      acc[dti] = __builtin_amdgcn_mfma_f32_32x32x16_bf16(vf[dti*2],     P0.s8, acc[dti], 0, 0, 0);
      acc[dti] = __builtin_amdgcn_mfma_f32_32x32x16_bf16(vf[dti*2 + 1], P1.s8, acc[dti], 0, 0, 0);
    }
    __builtin_amdgcn_s_setprio(0);
    __syncthreads();   // B2: sx reads done; K(kt+1) staging drained (vmcnt0 at barrier)
  }

  // ---- epilogue: normalize, transpose via LDS (alias), coalesced store ----
  float il = 1.0f / l;
  #pragma unroll
  for (int dti = 0; dti < 4; ++dti){
    #pragma unroll
    for (int g = 0; g < 4; ++g){
      short4_ w;
      #pragma unroll
      for (int u = 0; u < 4; ++u) w[u] = (short)f2bf(acc[dti][g*4 + u] * il);
      *(short4_*)&ostage[ql*536 + wv*128 + dti*32 + g*8 + hi*4] = w;
    }
  }
  __syncthreads();
  {
    int row = tid >> 3, c8b = tid & 7;
    #pragma unroll
    for (int i = 0; i < 8; ++i){
      int c8 = c8b + i*8;
      *(short8*)(Ob + (size_t)(q0 + row)*DV + c8*8) = *(const short8*)&ostage[row*536 + c8*8];
    }
  }
}

// ---------------- k4: out equi-linear + residual ----------------
// LDS: oT 69632B; fst (32768B) ALIASES oT after all MFMA reads complete. 2 blocks/CU.
__global__ __launch_bounds__(256) void k4_out(
    const unsigned short* __restrict__ O, const unsigned short* __restrict__ wob,
    const float* __restrict__ x, float* __restrict__ out){
  extern __shared__ char smem[];
  unsigned short* oT = (unsigned short*)smem;
  float* fst = (float*)smem;   // alias (used after barrier)

  int tid = threadIdx.x, wv = tid >> 6, lane = tid & 63, lm = lane & 15, kg = lane >> 4;
  int blk = blockIdx.x;
  int b = blk >> 7, t0 = (blk & 127) << 4;

  for (int ch = tid; ch < 4096; ch += 256){
    int hh = ch >> 10, t = (ch >> 6) & 15, c8 = ch & 63;
    short8 v = *(const short8*)(O + ((size_t)(b*H_ + hh)*T_ + (t0 + t))*512 + c8*8);
    int c = c8 >> 1, j0 = (c8 & 1)*8;
    int ci = hh*32 + c;
    #pragma unroll
    for (int d = 0; d < 8; ++d)
      oT[((j0 + d)*16 + t)*136 + ci] = (unsigned short)v[d];
  }
  __syncthreads();

  float accv[4][2][4];
  #pragma unroll
  for (int bi = 0; bi < 4; ++bi){
    int j  = (int)((BL_PK >> ((wv*4 + bi)*4)) & 15);
    int g  = (int)((GRADE_PK >> (j*4)) & 15);
    bool e0 = (E0MASK >> j) & 1;
    int eb = (int)((E0B_PK >> (j*4)) & 15);
    int sj = (int)((SRC_PK >> (j*4)) & 15);
    #pragma unroll
    for (int nt = 0; nt < 2; ++nt){
      int o = nt*16 + lm;
      float4_ acc = {0.f, 0.f, 0.f, 0.f};
      #pragma unroll
      for (int ks = 0; ks < 4; ++ks){
        short8 a = *(const short8*)&oT[(j*16 + lm)*136 + ks*32 + kg*8];
        short8 bfr = *(const short8*)(wob + ((size_t)(g*32 + o))*128 + ks*32 + kg*8);
        acc = __builtin_amdgcn_mfma_f32_16x16x32_bf16(a, bfr, acc, 0, 0, 0);
      }
      if (e0){
        #pragma unroll
        for (int ks = 0; ks < 4; ++ks){
          short8 a = *(const short8*)&oT[(sj*16 + lm)*136 + ks*32 + kg*8];
          short8 bfr = *(const short8*)(wob + ((size_t)(eb*32 + o))*128 + ks*32 + kg*8);
          acc = __builtin_amdgcn_mfma_f32_16x16x32_bf16(a, bfr, acc, 0, 0, 0);
        }
      }
      #pragma unroll
      for (int r = 0; r < 4; ++r) accv[bi][nt][r] = acc[r];
    }
  }
  __syncthreads();   // all oT reads done -> fst may overwrite
  #pragma unroll
  for (int bi = 0; bi < 4; ++bi){
    int j = (int)((BL_PK >> ((wv*4 + bi)*4)) & 15);
    #pragma unroll
    for (int nt = 0; nt < 2; ++nt){
      int o = nt*16 + lm;
      #pragma unroll
      for (int r = 0; r < 4; ++r){
        int t = kg*4 + r;
        fst[t*512 + o*16 + j] = accv[bi][nt][r];
      }
    }
  }
  __syncthreads();
  const float* xb = x + ((size_t)(b*T_ + t0))*512;
  float* ob = out + ((size_t)(b*T_ + t0))*512;
  for (int ch = tid; ch < 2048; ch += 256){
    float4_ v  = *(const float4_*)(fst + (size_t)ch*4);
    float4_ xv = *(const float4_*)(xb + (size_t)ch*4);
    *(float4_*)(ob + (size_t)ch*4) = v + xv;
  }
}

// ---------------- launcher ----------------
extern "C" void kernel_launch(void* const* d_in, const int* in_sizes, int n_in,
                              void* d_out, int out_size, void* d_ws, size_t ws_size,
                              hipStream_t stream){
  const float* x       = (const float*)d_in[0];
  const float* lnw     = (const float*)d_in[1];
  const float* w_qkv   = (const float*)d_in[2];
  const float* w_out   = (const float*)d_in[3];
  const float* mix_ipa = (const float*)d_in[4];
  const float* mix_daa = (const float*)d_in[5];
  float* out = (float*)d_out;

  // qf 27,262,976 | kf 27,262,976 | vt 33,554,432 | O 33,554,432
  // wqb 221,184 | wob 73,728 | wI 512 | wD 512  => 121,930,752
  if (ws_size < 121930752u) return;

  char* ws = (char*)d_ws;
  unsigned short* qf  = (unsigned short*)(ws + 0);
  unsigned short* kf  = (unsigned short*)(ws + 27262976);
  unsigned short* vt  = (unsigned short*)(ws + 54525952);
  unsigned short* O   = (unsigned short*)(ws + 88080384);
  unsigned short* wqb = (unsigned short*)(ws + 121634816);
  unsigned short* wob = (unsigned short*)(ws + 121856000);
  float* wI = (float*)(ws + 121929728);
  float* wD = (float*)(ws + 121930240);

  k0_prep<<<432, 256, 0, stream>>>(w_qkv, w_out, lnw, mix_ipa, mix_daa, wqb, wob, wI, wD);
  k1_qkv<<<512, 256, 75328, stream>>>(x, wqb, wI, wD, qf, kf, vt);
  k3_attn<<<1024, 256, 45056, stream>>>(qf, kf, vt, O);
  k4_out<<<512, 256, 69632, stream>>>(O, wob, x, out);
}

// Round 9
// 202.313 us; speedup vs baseline: 2.3807x; 2.3807x over previous
//
#include <hip/hip_runtime.h>

#define B_ 4
#define T_ 2048
#define C_ 32
#define H_ 4
#define DQK 416
#define DV 512
#define QSCALE 0.049029033784546f   // 1/sqrt(416)
#define LOG2E 1.4426950408889634f
// kf fragment layout: [bh][kt 64][sf 26][hi 2][key 32][8]
#define KF_BH 851968
#define KF_KT 13312      // shorts per kt tile (26*2*32*8)
// vt fragment layout: [bh][kt 64][dt 16][kh 2][grp 2][qll 32][8tok]
#define VT_KT 16384      // shorts per kt tile

typedef __attribute__((ext_vector_type(8))) short short8;
typedef __attribute__((ext_vector_type(4))) short short4_;
typedef __attribute__((ext_vector_type(4))) float float4_;
typedef __attribute__((ext_vector_type(16))) float f32x16;

#define GLOBAL_AS __attribute__((address_space(1)))
#define LDS_AS __attribute__((address_space(3)))

// packed nibble tables (blade j -> value), LSB nibble = j0
#define GRADE_PK 0x4333322222211110ULL
#define E0B_PK   0x8077700066600050ULL
#define SRC_PK   0xE0A9800043200000ULL
#define IPOS_PK  0x0700065400032100ULL
#define E0MASK   0xB8E2
#define INVMASK  0x471D
#define QKMASK   0x7F1D
#define BL_PK    0xEAFD98CB43762051ULL

__device__ __forceinline__ float bf2f(unsigned short u){
  union{unsigned int i; float f;} v; v.i = ((unsigned int)u) << 16; return v.f;
}
__device__ __forceinline__ unsigned short f2bf(float f){
  union{float f; unsigned int i;} v; v.f = f;
  unsigned int x = v.i;
  unsigned int r = x + 0x7FFFu + ((x >> 16) & 1u);
  return (unsigned short)(r >> 16);
}
__device__ __forceinline__ unsigned pkbf(float a, float b){
  unsigned ua = __float_as_uint(a) + 0x8000u;
  unsigned ub = __float_as_uint(b) + 0x8000u;
  return __builtin_amdgcn_perm(ub, ua, 0x07060302u);
}

// ---------------- k0: weight prep ----------------
__global__ void k0_prep(const float* __restrict__ w_qkv, const float* __restrict__ w_out,
                        const float* __restrict__ lnw, const float* __restrict__ mix_ipa,
                        const float* __restrict__ mix_daa,
                        unsigned short* __restrict__ wqb, unsigned short* __restrict__ wob,
                        float* __restrict__ wI, float* __restrict__ wD){
  int idx = blockIdx.x * 256 + threadIdx.x;
  if (idx < 9*384*32){
    int i = idx & 31;
    int rest = idx >> 5;
    int o = rest % 384;
    int bb = rest / 384;
    wqb[idx] = f2bf(w_qkv[(o*32 + i)*9 + bb] * lnw[i]);
  }
  if (idx < 9*32*128){
    int i = idx & 127;
    int rest = idx >> 7;
    int o = rest & 31;
    int bb = rest >> 5;
    wob[idx] = f2bf(w_out[(o*128 + i)*9 + bb]);
  }
  if (idx < 128){
    wI[idx] = __expf(mix_ipa[idx]);
    wD[idx] = __expf(mix_daa[idx]);
  }
}

// ---------------- k1: norm + QKV equi-linear + feature build ----------------
// LDS: xJ 20480 | invr 64 | red 512 | ost 4x13568 = 54272  => 75328B (2 blocks/CU)
__global__ __launch_bounds__(256) void k1_qkv(
    const float* __restrict__ x, const unsigned short* __restrict__ wqb,
    const float* __restrict__ wI, const float* __restrict__ wD,
    unsigned short* __restrict__ qf, unsigned short* __restrict__ kf,
    unsigned short* __restrict__ vt){
  extern __shared__ char smem[];
  unsigned short* xJ = (unsigned short*)smem;
  float* invr = (float*)(smem + 20480);
  float* red  = (float*)(smem + 20544);
  unsigned short* ostage = (unsigned short*)(smem + 21056);

  int tid = threadIdx.x;
  int tile = blockIdx.x;
  int b = tile >> 7;
  int t0 = (tile & 127) << 4;

  const float* xt = x + ((size_t)(b*T_ + t0)) * 512;
  #pragma unroll
  for (int pass = 0; pass < 8; ++pass){
    int g = tid + pass*256;
    int t = g >> 7, r = g & 127;
    int ci = r >> 2, j4 = (r & 3) << 2;
    float4_ v = *(const float4_*)(xt + (size_t)t*512 + ci*16 + j4);
    #pragma unroll
    for (int d = 0; d < 4; ++d){
      xJ[((j4 + d)*16 + t)*40 + ci] = f2bf(v[d]);
    }
  }
  __syncthreads();
  if (tid < 128){
    int t = tid >> 3, p = tid & 7;
    int j = (int)((0xEA984320u >> (p*4)) & 15u);
    float s = 0.f;
    #pragma unroll
    for (int i = 0; i < 32; ++i){
      float v = bf2f(xJ[(j*16 + t)*40 + i]);
      s += v*v;
    }
    red[t*8 + p] = s;
  }
  __syncthreads();
  if (tid < 16){
    float s = 0.f;
    #pragma unroll
    for (int p = 0; p < 8; ++p) s += red[tid*8 + p];
    invr[tid] = rsqrtf(s * (1.0f/32.0f) + 1e-5f);
  }
  __syncthreads();

  int wv = tid >> 6, lane = tid & 63, lm = lane & 15, kg = lane >> 4;
  unsigned short* ost = ostage + wv * 6784;   // 16 x 424 shorts
  int h = wv;
  int bh = b * H_ + h;
  unsigned short* vtb = vt + (size_t)bh * 64 * VT_KT;
  const float QSC2 = QSCALE * LOG2E;

  for (int s = 0; s < 3; ++s){
    int c12 = s*4 + h;
    float pr0[2][4], pr1[2][4], pr2[2][4];
    #pragma unroll
    for (int j = 0; j < 16; ++j){
      if (s < 2 && !((QKMASK >> j) & 1)) continue;
      int g  = (int)((GRADE_PK >> (j*4)) & 15);
      bool e0 = (E0MASK >> j) & 1;
      int eb = (int)((E0B_PK >> (j*4)) & 15);
      int sj = (int)((SRC_PK >> (j*4)) & 15);
      #pragma unroll
      for (int nt = 0; nt < 2; ++nt){
        int o = c12*32 + nt*16 + lm;
        float4_ acc = {0.f, 0.f, 0.f, 0.f};
        short8 a0 = *(const short8*)&xJ[(j*16 + lm)*40 + kg*8];
        short8 b0 = *(const short8*)&wqb[((size_t)(g*384 + o))*32 + kg*8];
        acc = __builtin_amdgcn_mfma_f32_16x16x32_bf16(a0, b0, acc, 0, 0, 0);
        if (e0){
          short8 a1 = *(const short8*)&xJ[(sj*16 + lm)*40 + kg*8];
          short8 b1 = *(const short8*)&wqb[((size_t)(eb*384 + o))*32 + kg*8];
          acc = __builtin_amdgcn_mfma_f32_16x16x32_bf16(a1, b1, acc, 0, 0, 0);
        }
        int c = nt*16 + lm;
        if (s == 2){
          // direct store to vt fragment layout (4 tokens contiguous in the 8-slot)
          int dim = c*16 + j;
          short4_ w;
          #pragma unroll
          for (int r = 0; r < 4; ++r) w[r] = (short)f2bf(acc[r] * invr[kg*4 + r]);
          int dt = dim >> 5, qll = dim & 31;
          size_t off = (size_t)(t0 >> 5)*VT_KT + dt*1024 + ((t0 >> 4) & 1)*512
                     + (kg >> 1)*256 + qll*8 + (kg & 1)*4;
          *(short4_*)(vtb + off) = w;
        } else {
          #pragma unroll
          for (int r = 0; r < 4; ++r){
            int t = kg*4 + r;
            float val = acc[r] * invr[t];
            if ((INVMASK >> j) & 1){
              int p = (int)((IPOS_PK >> (j*4)) & 15);
              float f = (s == 0) ? val * wI[h*32 + c] * QSC2 : val;
              ost[t*424 + c*8 + p] = f2bf(f);
            } else {
              float f = (s == 0) ? val * (2.0f * QSC2) * wD[h*32 + c] : val;
              ost[t*424 + 256 + c*5 + (j - 11)] = f2bf(f);
              if (j == 11) pr0[nt][r] = val;
              else if (j == 12) pr1[nt][r] = val;
              else pr2[nt][r] = val;
            }
          }
        }
      }
    }
    if (s < 2){
      // |p|^2 and const slots from registers (lane-local)
      #pragma unroll
      for (int nt = 0; nt < 2; ++nt){
        int c = nt*16 + lm;
        #pragma unroll
        for (int r = 0; r < 4; ++r){
          int t = kg*4 + r;
          float ps = pr0[nt][r]*pr0[nt][r] + pr1[nt][r]*pr1[nt][r] + pr2[nt][r]*pr2[nt][r];
          if (s == 0){
            float wd = wD[h*32 + c] * QSC2;
            ost[t*424 + 256 + c*5 + 3] = f2bf(-ps * wd);
            ost[t*424 + 256 + c*5 + 4] = f2bf(-wd);
          } else {
            ost[t*424 + 256 + c*5 + 3] = f2bf(1.0f);
            ost[t*424 + 256 + c*5 + 4] = f2bf(ps);
          }
        }
      }
      if (s == 0){
        unsigned short* dst = qf + ((size_t)bh*T_ + t0) * DQK;
        for (int ch = lane; ch < 832; ch += 64){
          int t = ch / 52, c8 = ch % 52;
          *(short8*)(dst + (size_t)t*DQK + c8*8) = *(const short8*)&ost[t*424 + c8*8];
        }
      } else {
        unsigned short* dst = kf + (size_t)bh * KF_BH;
        for (int ch = lane; ch < 832; ch += 64){
          int t = ch / 52, c8 = ch % 52;
          int f0 = c8 * 8;
          int hf2 = (f0 >= 208);
          int fl = f0 - hf2*208;
          int s_ = fl >> 4;
          int hi2 = (fl >> 3) & 1;
          int tt = t0 + t;
          size_t off = ((((size_t)(tt >> 5)*26 + hf2*13 + s_)*2 + hi2)*32 + (tt & 31))*8;
          *(short8*)(dst + off) = *(const short8*)&ost[t*424 + c8*8];
        }
      }
    }
  }
}

// ---------------- k3: flash attention — R5-proven structure ----------
// grid 1024 = [chunk desc 64][bhlo 2][xcd 8], block 256 (4 waves), 2 blocks/CU.
// Wave wv: QK feature quarter (sf {0-6,7-13,14-19,20-25}), PV dim quarter (wv*128..+128).
// K: global_load_lds DOUBLE-buffered (stage kt+1 after B1 into other buffer, drains at B2).
// V: direct-global fragment loads issued at iter top. sx single-buffered, 2 full barriers.
// LDS: kbuf 2x13312 shorts (53248B) | sx 4x[32][36] f32 (18432B) => 71680B
__device__ __forceinline__ void stageK2(const unsigned short* src, unsigned short* dst, int tid){
  const char* s = (const char*)src;
  char* d = (char*)dst;
  #pragma unroll
  for (int i = 0; i < 6; ++i)
    __builtin_amdgcn_global_load_lds((const GLOBAL_AS void*)(s + (i*256 + tid)*16),
                                     (LDS_AS void*)(d + (i*256 + tid)*16), 16, 0, 0);
  if (tid < 128)
    __builtin_amdgcn_global_load_lds((const GLOBAL_AS void*)(s + (1536 + tid)*16),
                                     (LDS_AS void*)(d + (1536 + tid)*16), 16, 0, 0);
}

__global__ __launch_bounds__(256, 2) void k3_attn(
    const unsigned short* __restrict__ qf, const unsigned short* __restrict__ kf,
    const unsigned short* __restrict__ vt, unsigned short* __restrict__ O){
  extern __shared__ char smem[];
  unsigned short* kbuf = (unsigned short*)smem;          // 2 x 13312 shorts
  float* sx = (float*)(smem + 53248);                    // 4 x 1152 f32
  unsigned short* ostage = (unsigned short*)smem;        // epilogue alias [32][536]

  int tid = threadIdx.x, wv = tid >> 6, lane = tid & 63;
  int ql = lane & 31, hi = lane >> 5;
  int blk = blockIdx.x;
  int bh = 2*(blk & 7) + ((blk >> 3) & 1);
  int chunk = 63 - (blk >> 4);
  int q0 = chunk * 32;

  const unsigned short* qfb = qf + (size_t)bh * T_ * DQK;
  const unsigned short* kfb = kf + (size_t)bh * KF_BH;
  const unsigned short* vtb = vt + (size_t)bh * 64 * VT_KT;
  unsigned short* Ob = O + (size_t)bh * T_ * DV;

  int FS = (wv < 2) ? wv*7 : 14 + (wv - 2)*6;     // sf base
  int FB = (wv < 2) ? wv*112 : 224 + (wv - 2)*96; // feature base

  // Q fragments (6 or 7 per wave)
  short8 qfr[7];
  {
    const unsigned short* qrow = qfb + (size_t)(q0 + ql)*DQK + FB + hi*8;
    #pragma unroll
    for (int s_ = 0; s_ < 6; ++s_) qfr[s_] = *(const short8*)(qrow + s_*16);
    if (wv < 2) qfr[6] = *(const short8*)(qrow + 96);
  }

  f32x16 acc[4];
  #pragma unroll
  for (int i = 0; i < 4; ++i){
    #pragma unroll
    for (int j = 0; j < 16; ++j) acc[i][j] = 0.f;
  }
  float m = -1e30f, l = 0.f;

  // prologue: stage K(0)
  stageK2(kfb, kbuf, tid);
  __syncthreads();

  for (int kt = 0; kt <= chunk; ++kt){
    int cur = kt & 1, nxt = cur ^ 1;
    // V fragment loads: issue early, consumed at PV (latency spans QK+B1+merge+softmax)
    short8 vf[8];
    {
      const unsigned short* vk = vtb + (size_t)kt*VT_KT + (wv*4)*1024 + lane*8;
      #pragma unroll
      for (int dti = 0; dti < 4; ++dti){
        vf[dti*2]     = *(const short8*)(vk + dti*1024);
        vf[dti*2 + 1] = *(const short8*)(vk + dti*1024 + 512);
      }
    }
    // QK quarter from kbuf[cur]
    f32x16 S;
    #pragma unroll
    for (int j = 0; j < 16; ++j) S[j] = 0.f;
    const unsigned short* kb = kbuf + cur*KF_KT;
    __builtin_amdgcn_s_setprio(1);
    #pragma unroll
    for (int s_ = 0; s_ < 6; ++s_){
      short8 kfr = *(const short8*)&kb[(FS + s_)*512 + hi*256 + ql*8];
      S = __builtin_amdgcn_mfma_f32_32x32x16_bf16(kfr, qfr[s_], S, 0, 0, 0);
    }
    if (wv < 2){
      short8 kfr = *(const short8*)&kb[(FS + 6)*512 + hi*256 + ql*8];
      S = __builtin_amdgcn_mfma_f32_32x32x16_bf16(kfr, qfr[6], S, 0, 0, 0);
    }
    __builtin_amdgcn_s_setprio(0);
    // write own quarter-scores
    {
      float* sxw = sx + wv*1152 + ql*36;
      #pragma unroll
      for (int g = 0; g < 4; ++g){
        float4_ w4;
        #pragma unroll
        for (int u = 0; u < 4; ++u) w4[u] = S[g*4 + u];
        *(float4_*)(sxw + g*8 + hi*4) = w4;
      }
    }
    __syncthreads();   // B1: quarters exchanged
    // merge 3 partners
    float s_[16];
    {
      int w1 = (wv + 1) & 3, w2 = (wv + 2) & 3, w3 = (wv + 3) & 3;
      #pragma unroll
      for (int g = 0; g < 4; ++g){
        float4_ a1 = *(const float4_*)(sx + w1*1152 + ql*36 + g*8 + hi*4);
        float4_ a2 = *(const float4_*)(sx + w2*1152 + ql*36 + g*8 + hi*4);
        float4_ a3 = *(const float4_*)(sx + w3*1152 + ql*36 + g*8 + hi*4);
        #pragma unroll
        for (int u = 0; u < 4; ++u) s_[g*4 + u] = S[g*4 + u] + a1[u] + a2[u] + a3[u];
      }
    }
    // stage next K into the OTHER buffer (drains at B2, hidden under softmax+PV)
    if (kt < chunk) stageK2(kfb + (size_t)(kt + 1)*KF_KT, kbuf + nxt*KF_KT, tid);
    // causal mask (diagonal tile)
    if (kt == chunk){
      #pragma unroll
      for (int r = 0; r < 16; ++r){
        int kr = (r & 3) + 8*(r >> 2) + 4*hi;
        if (kr > ql) s_[r] = -1e30f;
      }
    }
    // online softmax in exp2 domain (scores carry log2e from k1)
    float mx0 = fmaxf(fmaxf(s_[0], s_[1]), s_[2]);
    float mx1 = fmaxf(fmaxf(s_[3], s_[4]), s_[5]);
    float mx2 = fmaxf(fmaxf(s_[6], s_[7]), s_[8]);
    float mx3 = fmaxf(fmaxf(s_[9], s_[10]), s_[11]);
    float mx4 = fmaxf(fmaxf(s_[12], s_[13]), s_[14]);
    float pmax = fmaxf(fmaxf(fmaxf(mx0, mx1), fmaxf(mx2, mx3)), fmaxf(mx4, s_[15]));
    pmax = fmaxf(pmax, __shfl_xor(pmax, 32));
    if (!__all(pmax <= m + 11.54f)){
      float mn = fmaxf(m, pmax);
      float al = __builtin_amdgcn_exp2f(m - mn);
      m = mn; l *= al;
      #pragma unroll
      for (int dt = 0; dt < 4; ++dt) acc[dt] *= al;
    }
    float p[16]; float rs = 0.f;
    #pragma unroll
    for (int r = 0; r < 16; ++r){ p[r] = __builtin_amdgcn_exp2f(s_[r] - m); rs += p[r]; }
    rs += __shfl_xor(rs, 32);
    l += rs;
    // pack P^T into B-fragments
    unsigned A0 = pkbf(p[0],  p[1]);
    unsigned A1 = pkbf(p[2],  p[3]);
    unsigned A2 = pkbf(p[4],  p[5]);
    unsigned A3 = pkbf(p[6],  p[7]);
    unsigned A4 = pkbf(p[8],  p[9]);
    unsigned A5 = pkbf(p[10], p[11]);
    unsigned A6 = pkbf(p[12], p[13]);
    unsigned A7 = pkbf(p[14], p[15]);
    unsigned S0 = __shfl_xor((int)A0, 32), S2 = __shfl_xor((int)A2, 32);
    unsigned S1 = __shfl_xor((int)A1, 32), S3 = __shfl_xor((int)A3, 32);
    unsigned S4 = __shfl_xor((int)A4, 32), S6 = __shfl_xor((int)A6, 32);
    unsigned S5 = __shfl_xor((int)A5, 32), S7 = __shfl_xor((int)A7, 32);
    union { unsigned u[4]; short8 s8; } P0, P1;
    P0.u[0] = hi ? S2 : A0;  P0.u[1] = hi ? S3 : A1;
    P0.u[2] = hi ? A2 : S0;  P0.u[3] = hi ? A3 : S1;
    P1.u[0] = hi ? S6 : A4;  P1.u[1] = hi ? S7 : A5;
    P1.u[2] = hi ? A6 : S4;  P1.u[3] = hi ? A7 : S5;
    // PV: own 128-dim quarter
    __builtin_amdgcn_s_setprio(1);
    #pragma unroll
    for (int dti = 0; dti < 4; ++dti){
      acc[dti] = __builtin_amdgcn_mfma_f32_32x32x16_bf16(vf[dti*2],     P0.s8, acc[dti], 0, 0, 0);
      acc[dti] = __builtin_amdgcn_mfma_f32_32x32x16_bf16(vf[dti*2 + 1], P1.s8, acc[dti], 0, 0, 0);
    }
    __builtin_amdgcn_s_setprio(0);
    __syncthreads();   // B2: sx reads done; K(kt+1) staging drained (vmcnt0 at barrier)
  }

  // ---- epilogue: normalize, transpose via LDS (alias), coalesced store ----
  float il = 1.0f / l;
  #pragma unroll
  for (int dti = 0; dti < 4; ++dti){
    #pragma unroll
    for (int g = 0; g < 4; ++g){
      short4_ w;
      #pragma unroll
      for (int u = 0; u < 4; ++u) w[u] = (short)f2bf(acc[dti][g*4 + u] * il);
      *(short4_*)&ostage[ql*536 + wv*128 + dti*32 + g*8 + hi*4] = w;
    }
  }
  __syncthreads();
  {
    int row = tid >> 3, c8b = tid & 7;
    #pragma unroll
    for (int i = 0; i < 8; ++i){
      int c8 = c8b + i*8;
      *(short8*)(Ob + (size_t)(q0 + row)*DV + c8*8) = *(const short8*)&ostage[row*536 + c8*8];
    }
  }
}

// ---------------- k4: out equi-linear + residual ----------------
// LDS: oT 69632B; fst (32768B) ALIASES oT after all MFMA reads complete. 2 blocks/CU.
__global__ __launch_bounds__(256) void k4_out(
    const unsigned short* __restrict__ O, const unsigned short* __restrict__ wob,
    const float* __restrict__ x, float* __restrict__ out){
  extern __shared__ char smem[];
  unsigned short* oT = (unsigned short*)smem;
  float* fst = (float*)smem;   // alias (used after barrier)

  int tid = threadIdx.x, wv = tid >> 6, lane = tid & 63, lm = lane & 15, kg = lane >> 4;
  int blk = blockIdx.x;
  int b = blk >> 7, t0 = (blk & 127) << 4;

  for (int ch = tid; ch < 4096; ch += 256){
    int hh = ch >> 10, t = (ch >> 6) & 15, c8 = ch & 63;
    short8 v = *(const short8*)(O + ((size_t)(b*H_ + hh)*T_ + (t0 + t))*512 + c8*8);
    int c = c8 >> 1, j0 = (c8 & 1)*8;
    int ci = hh*32 + c;
    #pragma unroll
    for (int d = 0; d < 8; ++d)
      oT[((j0 + d)*16 + t)*136 + ci] = (unsigned short)v[d];
  }
  __syncthreads();

  float accv[4][2][4];
  #pragma unroll
  for (int bi = 0; bi < 4; ++bi){
    int j  = (int)((BL_PK >> ((wv*4 + bi)*4)) & 15);
    int g  = (int)((GRADE_PK >> (j*4)) & 15);
    bool e0 = (E0MASK >> j) & 1;
    int eb = (int)((E0B_PK >> (j*4)) & 15);
    int sj = (int)((SRC_PK >> (j*4)) & 15);
    #pragma unroll
    for (int nt = 0; nt < 2; ++nt){
      int o = nt*16 + lm;
      float4_ acc = {0.f, 0.f, 0.f, 0.f};
      #pragma unroll
      for (int ks = 0; ks < 4; ++ks){
        short8 a = *(const short8*)&oT[(j*16 + lm)*136 + ks*32 + kg*8];
        short8 bfr = *(const short8*)(wob + ((size_t)(g*32 + o))*128 + ks*32 + kg*8);
        acc = __builtin_amdgcn_mfma_f32_16x16x32_bf16(a, bfr, acc, 0, 0, 0);
      }
      if (e0){
        #pragma unroll
        for (int ks = 0; ks < 4; ++ks){
          short8 a = *(const short8*)&oT[(sj*16 + lm)*136 + ks*32 + kg*8];
          short8 bfr = *(const short8*)(wob + ((size_t)(eb*32 + o))*128 + ks*32 + kg*8);
          acc = __builtin_amdgcn_mfma_f32_16x16x32_bf16(a, bfr, acc, 0, 0, 0);
        }
      }
      #pragma unroll
      for (int r = 0; r < 4; ++r) accv[bi][nt][r] = acc[r];
    }
  }
  __syncthreads();   // all oT reads done -> fst may overwrite
  #pragma unroll
  for (int bi = 0; bi < 4; ++bi){
    int j = (int)((BL_PK >> ((wv*4 + bi)*4)) & 15);
    #pragma unroll
    for (int nt = 0; nt < 2; ++nt){
      int o = nt*16 + lm;
      #pragma unroll
      for (int r = 0; r < 4; ++r){
        int t = kg*4 + r;
        fst[t*512 + o*16 + j] = accv[bi][nt][r];
      }
    }
  }
  __syncthreads();
  const float* xb = x + ((size_t)(b*T_ + t0))*512;
  float* ob = out + ((size_t)(b*T_ + t0))*512;
  for (int ch = tid; ch < 2048; ch += 256){
    float4_ v  = *(const float4_*)(fst + (size_t)ch*4);
    float4_ xv = *(const float4_*)(xb + (size_t)ch*4);
    *(float4_*)(ob + (size_t)ch*4) = v + xv;
  }
}

// ---------------- launcher ----------------
extern "C" void kernel_launch(void* const* d_in, const int* in_sizes, int n_in,
                              void* d_out, int out_size, void* d_ws, size_t ws_size,
                              hipStream_t stream){
  const float* x       = (const float*)d_in[0];
  const float* lnw     = (const float*)d_in[1];
  const float* w_qkv   = (const float*)d_in[2];
  const float* w_out   = (const float*)d_in[3];
  const float* mix_ipa = (const float*)d_in[4];
  const float* mix_daa = (const float*)d_in[5];
  float* out = (float*)d_out;

  // qf 27,262,976 | kf 27,262,976 | vt 33,554,432 | O 33,554,432
  // wqb 221,184 | wob 73,728 | wI 512 | wD 512  => 121,930,752
  if (ws_size < 121930752u) return;

  char* ws = (char*)d_ws;
  unsigned short* qf  = (unsigned short*)(ws + 0);
  unsigned short* kf  = (unsigned short*)(ws + 27262976);
  unsigned short* vt  = (unsigned short*)(ws + 54525952);
  unsigned short* O   = (unsigned short*)(ws + 88080384);
  unsigned short* wqb = (unsigned short*)(ws + 121634816);
  unsigned short* wob = (unsigned short*)(ws + 121856000);
  float* wI = (float*)(ws + 121929728);
  float* wD = (float*)(ws + 121930240);

  k0_prep<<<432, 256, 0, stream>>>(w_qkv, w_out, lnw, mix_ipa, mix_daa, wqb, wob, wI, wD);
  k1_qkv<<<512, 256, 75328, stream>>>(x, wqb, wI, wD, qf, kf, vt);
  k3_attn<<<1024, 256, 71680, stream>>>(qf, kf, vt, O);
  k4_out<<<512, 256, 69632, stream>>>(O, wob, x, out);
}

// Round 11
// 187.240 us; speedup vs baseline: 2.5724x; 1.0805x over previous
//
#include <hip/hip_runtime.h>

#define B_ 4
#define T_ 2048
#define C_ 32
#define H_ 4
#define DQK 416
#define DV 512
#define QSCALE 0.049029033784546f   // 1/sqrt(416)
#define LOG2E 1.4426950408889634f
// kf fragment layout: [bh][kt 64][sf 26][hi 2][key 32][8]
#define KF_BH 851968
#define KF_KT 13312      // shorts per kt tile (26*2*32*8)
// vt fragment layout: [bh][kt 64][dt 16][kh 2][grp 2][qll 32][8tok]
#define VT_KT 16384      // shorts per kt tile

typedef __attribute__((ext_vector_type(8))) short short8;
typedef __attribute__((ext_vector_type(4))) short short4_;
typedef __attribute__((ext_vector_type(4))) float float4_;
typedef __attribute__((ext_vector_type(16))) float f32x16;

// packed nibble tables (blade j -> value), LSB nibble = j0
#define GRADE_PK 0x4333322222211110ULL
#define E0B_PK   0x8077700066600050ULL
#define SRC_PK   0xE0A9800043200000ULL
#define IPOS_PK  0x0700065400032100ULL
#define E0MASK   0xB8E2
#define INVMASK  0x471D
#define QKMASK   0x7F1D
#define BL_PK    0xEAFD98CB43762051ULL

__device__ __forceinline__ float bf2f(unsigned short u){
  union{unsigned int i; float f;} v; v.i = ((unsigned int)u) << 16; return v.f;
}
__device__ __forceinline__ unsigned short f2bf(float f){
  union{float f; unsigned int i;} v; v.f = f;
  unsigned int x = v.i;
  unsigned int r = x + 0x7FFFu + ((x >> 16) & 1u);
  return (unsigned short)(r >> 16);
}
__device__ __forceinline__ unsigned pkbf(float a, float b){
  unsigned ua = __float_as_uint(a) + 0x8000u;
  unsigned ub = __float_as_uint(b) + 0x8000u;
  return __builtin_amdgcn_perm(ub, ua, 0x07060302u);
}

// ---------------- k0: weight prep ----------------
__global__ void k0_prep(const float* __restrict__ w_qkv, const float* __restrict__ w_out,
                        const float* __restrict__ lnw, const float* __restrict__ mix_ipa,
                        const float* __restrict__ mix_daa,
                        unsigned short* __restrict__ wqb, unsigned short* __restrict__ wob,
                        float* __restrict__ wI, float* __restrict__ wD){
  int idx = blockIdx.x * 256 + threadIdx.x;
  if (idx < 9*384*32){
    int i = idx & 31;
    int rest = idx >> 5;
    int o = rest % 384;
    int bb = rest / 384;
    wqb[idx] = f2bf(w_qkv[(o*32 + i)*9 + bb] * lnw[i]);
  }
  if (idx < 9*32*128){
    int i = idx & 127;
    int rest = idx >> 7;
    int o = rest & 31;
    int bb = rest >> 5;
    wob[idx] = f2bf(w_out[(o*128 + i)*9 + bb]);
  }
  if (idx < 128){
    wI[idx] = __expf(mix_ipa[idx]);
    wD[idx] = __expf(mix_daa[idx]);
  }
}

// ---------------- k1: norm + QKV equi-linear + feature build ----------------
// LDS: xJ 20480 | invr 64 | red 512 | ost 4x13568 = 54272  => 75328B (2 blocks/CU)
__global__ __launch_bounds__(256) void k1_qkv(
    const float* __restrict__ x, const unsigned short* __restrict__ wqb,
    const float* __restrict__ wI, const float* __restrict__ wD,
    unsigned short* __restrict__ qf, unsigned short* __restrict__ kf,
    unsigned short* __restrict__ vt){
  extern __shared__ char smem[];
  unsigned short* xJ = (unsigned short*)smem;
  float* invr = (float*)(smem + 20480);
  float* red  = (float*)(smem + 20544);
  unsigned short* ostage = (unsigned short*)(smem + 21056);

  int tid = threadIdx.x;
  int tile = blockIdx.x;
  int b = tile >> 7;
  int t0 = (tile & 127) << 4;

  const float* xt = x + ((size_t)(b*T_ + t0)) * 512;
  #pragma unroll
  for (int pass = 0; pass < 8; ++pass){
    int g = tid + pass*256;
    int t = g >> 7, r = g & 127;
    int ci = r >> 2, j4 = (r & 3) << 2;
    float4_ v = *(const float4_*)(xt + (size_t)t*512 + ci*16 + j4);
    #pragma unroll
    for (int d = 0; d < 4; ++d){
      xJ[((j4 + d)*16 + t)*40 + ci] = f2bf(v[d]);
    }
  }
  __syncthreads();
  if (tid < 128){
    int t = tid >> 3, p = tid & 7;
    int j = (int)((0xEA984320u >> (p*4)) & 15u);
    float s = 0.f;
    #pragma unroll
    for (int i = 0; i < 32; ++i){
      float v = bf2f(xJ[(j*16 + t)*40 + i]);
      s += v*v;
    }
    red[t*8 + p] = s;
  }
  __syncthreads();
  if (tid < 16){
    float s = 0.f;
    #pragma unroll
    for (int p = 0; p < 8; ++p) s += red[tid*8 + p];
    invr[tid] = rsqrtf(s * (1.0f/32.0f) + 1e-5f);
  }
  __syncthreads();

  int wv = tid >> 6, lane = tid & 63, lm = lane & 15, kg = lane >> 4;
  unsigned short* ost = ostage + wv * 6784;   // 16 x 424 shorts
  int h = wv;
  int bh = b * H_ + h;
  unsigned short* vtb = vt + (size_t)bh * 64 * VT_KT;
  const float QSC2 = QSCALE * LOG2E;

  for (int s = 0; s < 3; ++s){
    int c12 = s*4 + h;
    float pr0[2][4], pr1[2][4], pr2[2][4];
    #pragma unroll
    for (int j = 0; j < 16; ++j){
      if (s < 2 && !((QKMASK >> j) & 1)) continue;
      int g  = (int)((GRADE_PK >> (j*4)) & 15);
      bool e0 = (E0MASK >> j) & 1;
      int eb = (int)((E0B_PK >> (j*4)) & 15);
      int sj = (int)((SRC_PK >> (j*4)) & 15);
      #pragma unroll
      for (int nt = 0; nt < 2; ++nt){
        int o = c12*32 + nt*16 + lm;
        float4_ acc = {0.f, 0.f, 0.f, 0.f};
        short8 a0 = *(const short8*)&xJ[(j*16 + lm)*40 + kg*8];
        short8 b0 = *(const short8*)&wqb[((size_t)(g*384 + o))*32 + kg*8];
        acc = __builtin_amdgcn_mfma_f32_16x16x32_bf16(a0, b0, acc, 0, 0, 0);
        if (e0){
          short8 a1 = *(const short8*)&xJ[(sj*16 + lm)*40 + kg*8];
          short8 b1 = *(const short8*)&wqb[((size_t)(eb*384 + o))*32 + kg*8];
          acc = __builtin_amdgcn_mfma_f32_16x16x32_bf16(a1, b1, acc, 0, 0, 0);
        }
        int c = nt*16 + lm;
        if (s == 2){
          // direct store to vt fragment layout (4 tokens contiguous in the 8-slot)
          int dim = c*16 + j;
          short4_ w;
          #pragma unroll
          for (int r = 0; r < 4; ++r) w[r] = (short)f2bf(acc[r] * invr[kg*4 + r]);
          int dt = dim >> 5, qll = dim & 31;
          size_t off = (size_t)(t0 >> 5)*VT_KT + dt*1024 + ((t0 >> 4) & 1)*512
                     + (kg >> 1)*256 + qll*8 + (kg & 1)*4;
          *(short4_*)(vtb + off) = w;
        } else {
          #pragma unroll
          for (int r = 0; r < 4; ++r){
            int t = kg*4 + r;
            float val = acc[r] * invr[t];
            if ((INVMASK >> j) & 1){
              int p = (int)((IPOS_PK >> (j*4)) & 15);
              float f = (s == 0) ? val * wI[h*32 + c] * QSC2 : val;
              ost[t*424 + c*8 + p] = f2bf(f);
            } else {
              float f = (s == 0) ? val * (2.0f * QSC2) * wD[h*32 + c] : val;
              ost[t*424 + 256 + c*5 + (j - 11)] = f2bf(f);
              if (j == 11) pr0[nt][r] = val;
              else if (j == 12) pr1[nt][r] = val;
              else pr2[nt][r] = val;
            }
          }
        }
      }
    }
    if (s < 2){
      // |p|^2 and const slots from registers (lane-local)
      #pragma unroll
      for (int nt = 0; nt < 2; ++nt){
        int c = nt*16 + lm;
        #pragma unroll
        for (int r = 0; r < 4; ++r){
          int t = kg*4 + r;
          float ps = pr0[nt][r]*pr0[nt][r] + pr1[nt][r]*pr1[nt][r] + pr2[nt][r]*pr2[nt][r];
          if (s == 0){
            float wd = wD[h*32 + c] * QSC2;
            ost[t*424 + 256 + c*5 + 3] = f2bf(-ps * wd);
            ost[t*424 + 256 + c*5 + 4] = f2bf(-wd);
          } else {
            ost[t*424 + 256 + c*5 + 3] = f2bf(1.0f);
            ost[t*424 + 256 + c*5 + 4] = f2bf(ps);
          }
        }
      }
      if (s == 0){
        unsigned short* dst = qf + ((size_t)bh*T_ + t0) * DQK;
        for (int ch = lane; ch < 832; ch += 64){
          int t = ch / 52, c8 = ch % 52;
          *(short8*)(dst + (size_t)t*DQK + c8*8) = *(const short8*)&ost[t*424 + c8*8];
        }
      } else {
        unsigned short* dst = kf + (size_t)bh * KF_BH;
        for (int ch = lane; ch < 832; ch += 64){
          int t = ch / 52, c8 = ch % 52;
          int f0 = c8 * 8;
          int hf2 = (f0 >= 208);
          int fl = f0 - hf2*208;
          int s_ = fl >> 4;
          int hi2 = (fl >> 3) & 1;
          int tt = t0 + t;
          size_t off = ((((size_t)(tt >> 5)*26 + hf2*13 + s_)*2 + hi2)*32 + (tt & 31))*8;
          *(short8*)(dst + off) = *(const short8*)&ost[t*424 + c8*8];
        }
      }
    }
  }
}

// ---------------- k3: flash attention — R9 sync skeleton, K in registers ----------
// grid 1024 = [chunk desc 64][bhlo 2][xcd 8], block 256 (4 waves), 2 blocks/CU.
// Wave wv: QK feature quarter (sf {0-6,7-13,14-19,20-25}), PV dim quarter (wv*128..+128).
// K: per-wave direct-global fragment loads into registers, prefetched into kn[] AFTER B1
// (same issue point as R9's global_load_lds staging; latency hidden under softmax+PV,
// drained by B2's vmcnt(0)), rotated into kc[] after B2. No K LDS round trip.
// V: direct fragment loads at iter top. sx single-buffered, two full __syncthreads.
// LDS: sx 4x[32][36] f32 = 18432B; epilogue ostage alias needs 34304B => 34816B
__global__ __launch_bounds__(256, 2) void k3_attn(
    const unsigned short* __restrict__ qf, const unsigned short* __restrict__ kf,
    const unsigned short* __restrict__ vt, unsigned short* __restrict__ O){
  extern __shared__ char smem[];
  float* sx = (float*)smem;                        // 4 x 1152 f32
  unsigned short* ostage = (unsigned short*)smem;  // epilogue alias [32][536]

  int tid = threadIdx.x, wv = tid >> 6, lane = tid & 63;
  int ql = lane & 31, hi = lane >> 5;
  int blk = blockIdx.x;
  int bh = 2*(blk & 7) + ((blk >> 3) & 1);
  int chunk = 63 - (blk >> 4);
  int q0 = chunk * 32;

  const unsigned short* qfb = qf + (size_t)bh * T_ * DQK;
  const unsigned short* vtb = vt + (size_t)bh * 64 * VT_KT;
  unsigned short* Ob = O + (size_t)bh * T_ * DV;

  int FS = (wv < 2) ? wv*7 : 14 + (wv - 2)*6;     // sf base
  int FB = (wv < 2) ? wv*112 : 224 + (wv - 2)*96; // feature base
  // per-lane K fragment pointer (this wave's feature quarter)
  const unsigned short* kfw = kf + (size_t)bh * KF_BH + (size_t)FS*512 + hi*256 + ql*8;

  // Q fragments (6 or 7 per wave)
  short8 qfr[7];
  {
    const unsigned short* qrow = qfb + (size_t)(q0 + ql)*DQK + FB + hi*8;
    #pragma unroll
    for (int s_ = 0; s_ < 6; ++s_) qfr[s_] = *(const short8*)(qrow + s_*16);
    if (wv < 2) qfr[6] = *(const short8*)(qrow + 96);
  }

  f32x16 acc[4];
  #pragma unroll
  for (int i = 0; i < 4; ++i){
    #pragma unroll
    for (int j = 0; j < 16; ++j) acc[i][j] = 0.f;
  }
  float m = -1e30f, l = 0.f;

  // prologue: K(0) -> kc (direct loads)
  short8 kc[7];
  {
    #pragma unroll
    for (int i = 0; i < 6; ++i) kc[i] = *(const short8*)(kfw + i*512);
    if (wv < 2) kc[6] = *(const short8*)(kfw + 3072);
  }

  for (int kt = 0; kt <= chunk; ++kt){
    // V fragment loads: issue early, consumed at PV
    short8 vf[8];
    {
      const unsigned short* vk = vtb + (size_t)kt*VT_KT + (wv*4)*1024 + lane*8;
      #pragma unroll
      for (int dti = 0; dti < 4; ++dti){
        vf[dti*2]     = *(const short8*)(vk + dti*1024);
        vf[dti*2 + 1] = *(const short8*)(vk + dti*1024 + 512);
      }
    }
    // QK quarter from registers
    f32x16 S;
    #pragma unroll
    for (int j = 0; j < 16; ++j) S[j] = 0.f;
    __builtin_amdgcn_s_setprio(1);
    #pragma unroll
    for (int s_ = 0; s_ < 6; ++s_)
      S = __builtin_amdgcn_mfma_f32_32x32x16_bf16(kc[s_], qfr[s_], S, 0, 0, 0);
    if (wv < 2)
      S = __builtin_amdgcn_mfma_f32_32x32x16_bf16(kc[6], qfr[6], S, 0, 0, 0);
    __builtin_amdgcn_s_setprio(0);
    // write own quarter-scores
    {
      float* sxw = sx + wv*1152 + ql*36;
      #pragma unroll
      for (int g = 0; g < 4; ++g){
        float4_ w4;
        #pragma unroll
        for (int u = 0; u < 4; ++u) w4[u] = S[g*4 + u];
        *(float4_*)(sxw + g*8 + hi*4) = w4;
      }
    }
    __syncthreads();   // B1: quarters exchanged
    // merge 3 partners
    float s_[16];
    {
      int w1 = (wv + 1) & 3, w2 = (wv + 2) & 3, w3 = (wv + 3) & 3;
      #pragma unroll
      for (int g = 0; g < 4; ++g){
        float4_ a1 = *(const float4_*)(sx + w1*1152 + ql*36 + g*8 + hi*4);
        float4_ a2 = *(const float4_*)(sx + w2*1152 + ql*36 + g*8 + hi*4);
        float4_ a3 = *(const float4_*)(sx + w3*1152 + ql*36 + g*8 + hi*4);
        #pragma unroll
        for (int u = 0; u < 4; ++u) s_[g*4 + u] = S[g*4 + u] + a1[u] + a2[u] + a3[u];
      }
    }
    // prefetch K(kt+1) into kn (issued here = R9's staging point; drains at B2,
    // latency hidden under mask+softmax+pack+PV)
    short8 kn[7];
    if (kt < chunk){
      const unsigned short* kk = kfw + (size_t)(kt + 1)*KF_KT;
      #pragma unroll
      for (int i = 0; i < 6; ++i) kn[i] = *(const short8*)(kk + i*512);
      if (wv < 2) kn[6] = *(const short8*)(kk + 3072);
    }
    // causal mask (diagonal tile)
    if (kt == chunk){
      #pragma unroll
      for (int r = 0; r < 16; ++r){
        int kr = (r & 3) + 8*(r >> 2) + 4*hi;
        if (kr > ql) s_[r] = -1e30f;
      }
    }
    // online softmax in exp2 domain (scores carry log2e from k1)
    float mx0 = fmaxf(fmaxf(s_[0], s_[1]), s_[2]);
    float mx1 = fmaxf(fmaxf(s_[3], s_[4]), s_[5]);
    float mx2 = fmaxf(fmaxf(s_[6], s_[7]), s_[8]);
    float mx3 = fmaxf(fmaxf(s_[9], s_[10]), s_[11]);
    float mx4 = fmaxf(fmaxf(s_[12], s_[13]), s_[14]);
    float pmax = fmaxf(fmaxf(fmaxf(mx0, mx1), fmaxf(mx2, mx3)), fmaxf(mx4, s_[15]));
    pmax = fmaxf(pmax, __shfl_xor(pmax, 32));
    if (!__all(pmax <= m + 11.54f)){
      float mn = fmaxf(m, pmax);
      float al = __builtin_amdgcn_exp2f(m - mn);
      m = mn; l *= al;
      #pragma unroll
      for (int dt = 0; dt < 4; ++dt) acc[dt] *= al;
    }
    float p[16]; float rs = 0.f;
    #pragma unroll
    for (int r = 0; r < 16; ++r){ p[r] = __builtin_amdgcn_exp2f(s_[r] - m); rs += p[r]; }
    rs += __shfl_xor(rs, 32);
    l += rs;
    // pack P^T into B-fragments
    unsigned A0 = pkbf(p[0],  p[1]);
    unsigned A1 = pkbf(p[2],  p[3]);
    unsigned A2 = pkbf(p[4],  p[5]);
    unsigned A3 = pkbf(p[6],  p[7]);
    unsigned A4 = pkbf(p[8],  p[9]);
    unsigned A5 = pkbf(p[10], p[11]);
    unsigned A6 = pkbf(p[12], p[13]);
    unsigned A7 = pkbf(p[14], p[15]);
    unsigned S0 = __shfl_xor((int)A0, 32), S2 = __shfl_xor((int)A2, 32);
    unsigned S1 = __shfl_xor((int)A1, 32), S3 = __shfl_xor((int)A3, 32);
    unsigned S4 = __shfl_xor((int)A4, 32), S6 = __shfl_xor((int)A6, 32);
    unsigned S5 = __shfl_xor((int)A5, 32), S7 = __shfl_xor((int)A7, 32);
    union { unsigned u[4]; short8 s8; } P0, P1;
    P0.u[0] = hi ? S2 : A0;  P0.u[1] = hi ? S3 : A1;
    P0.u[2] = hi ? A2 : S0;  P0.u[3] = hi ? A3 : S1;
    P1.u[0] = hi ? S6 : A4;  P1.u[1] = hi ? S7 : A5;
    P1.u[2] = hi ? A6 : S4;  P1.u[3] = hi ? A7 : S5;
    // PV: own 128-dim quarter
    __builtin_amdgcn_s_setprio(1);
    #pragma unroll
    for (int dti = 0; dti < 4; ++dti){
      acc[dti] = __builtin_amdgcn_mfma_f32_32x32x16_bf16(vf[dti*2],     P0.s8, acc[dti], 0, 0, 0);
      acc[dti] = __builtin_amdgcn_mfma_f32_32x32x16_bf16(vf[dti*2 + 1], P1.s8, acc[dti], 0, 0, 0);
    }
    __builtin_amdgcn_s_setprio(0);
    __syncthreads();   // B2: sx reads done (next write safe); kn loads drained
    // rotate prefetched K into place
    if (kt < chunk){
      #pragma unroll
      for (int i = 0; i < 6; ++i) kc[i] = kn[i];
      if (wv < 2) kc[6] = kn[6];
    }
  }

  // ---- epilogue: normalize, transpose via LDS (alias), coalesced store ----
  float il = 1.0f / l;
  #pragma unroll
  for (int dti = 0; dti < 4; ++dti){
    #pragma unroll
    for (int g = 0; g < 4; ++g){
      short4_ w;
      #pragma unroll
      for (int u = 0; u < 4; ++u) w[u] = (short)f2bf(acc[dti][g*4 + u] * il);
      *(short4_*)&ostage[ql*536 + wv*128 + dti*32 + g*8 + hi*4] = w;
    }
  }
  __syncthreads();
  {
    int row = tid >> 3, c8b = tid & 7;
    #pragma unroll
    for (int i = 0; i < 8; ++i){
      int c8 = c8b + i*8;
      *(short8*)(Ob + (size_t)(q0 + row)*DV + c8*8) = *(const short8*)&ostage[row*536 + c8*8];
    }
  }
}

// ---------------- k4: out equi-linear + residual ----------------
// LDS: oT 69632B; fst (32768B) ALIASES oT after all MFMA reads complete. 2 blocks/CU.
__global__ __launch_bounds__(256) void k4_out(
    const unsigned short* __restrict__ O, const unsigned short* __restrict__ wob,
    const float* __restrict__ x, float* __restrict__ out){
  extern __shared__ char smem[];
  unsigned short* oT = (unsigned short*)smem;
  float* fst = (float*)smem;   // alias (used after barrier)

  int tid = threadIdx.x, wv = tid >> 6, lane = tid & 63, lm = lane & 15, kg = lane >> 4;
  int blk = blockIdx.x;
  int b = blk >> 7, t0 = (blk & 127) << 4;

  for (int ch = tid; ch < 4096; ch += 256){
    int hh = ch >> 10, t = (ch >> 6) & 15, c8 = ch & 63;
    short8 v = *(const short8*)(O + ((size_t)(b*H_ + hh)*T_ + (t0 + t))*512 + c8*8);
    int c = c8 >> 1, j0 = (c8 & 1)*8;
    int ci = hh*32 + c;
    #pragma unroll
    for (int d = 0; d < 8; ++d)
      oT[((j0 + d)*16 + t)*136 + ci] = (unsigned short)v[d];
  }
  __syncthreads();

  float accv[4][2][4];
  #pragma unroll
  for (int bi = 0; bi < 4; ++bi){
    int j  = (int)((BL_PK >> ((wv*4 + bi)*4)) & 15);
    int g  = (int)((GRADE_PK >> (j*4)) & 15);
    bool e0 = (E0MASK >> j) & 1;
    int eb = (int)((E0B_PK >> (j*4)) & 15);
    int sj = (int)((SRC_PK >> (j*4)) & 15);
    #pragma unroll
    for (int nt = 0; nt < 2; ++nt){
      int o = nt*16 + lm;
      float4_ acc = {0.f, 0.f, 0.f, 0.f};
      #pragma unroll
      for (int ks = 0; ks < 4; ++ks){
        short8 a = *(const short8*)&oT[(j*16 + lm)*136 + ks*32 + kg*8];
        short8 bfr = *(const short8*)(wob + ((size_t)(g*32 + o))*128 + ks*32 + kg*8);
        acc = __builtin_amdgcn_mfma_f32_16x16x32_bf16(a, bfr, acc, 0, 0, 0);
      }
      if (e0){
        #pragma unroll
        for (int ks = 0; ks < 4; ++ks){
          short8 a = *(const short8*)&oT[(sj*16 + lm)*136 + ks*32 + kg*8];
          short8 bfr = *(const short8*)(wob + ((size_t)(eb*32 + o))*128 + ks*32 + kg*8);
          acc = __builtin_amdgcn_mfma_f32_16x16x32_bf16(a, bfr, acc, 0, 0, 0);
        }
      }
      #pragma unroll
      for (int r = 0; r < 4; ++r) accv[bi][nt][r] = acc[r];
    }
  }
  __syncthreads();   // all oT reads done -> fst may overwrite
  #pragma unroll
  for (int bi = 0; bi < 4; ++bi){
    int j = (int)((BL_PK >> ((wv*4 + bi)*4)) & 15);
    #pragma unroll
    for (int nt = 0; nt < 2; ++nt){
      int o = nt*16 + lm;
      #pragma unroll
      for (int r = 0; r < 4; ++r){
        int t = kg*4 + r;
        fst[t*512 + o*16 + j] = accv[bi][nt][r];
      }
    }
  }
  __syncthreads();
  const float* xb = x + ((size_t)(b*T_ + t0))*512;
  float* ob = out + ((size_t)(b*T_ + t0))*512;
  for (int ch = tid; ch < 2048; ch += 256){
    float4_ v  = *(const float4_*)(fst + (size_t)ch*4);
    float4_ xv = *(const float4_*)(xb + (size_t)ch*4);
    *(float4_*)(ob + (size_t)ch*4) = v + xv;
  }
}

// ---------------- launcher ----------------
extern "C" void kernel_launch(void* const* d_in, const int* in_sizes, int n_in,
                              void* d_out, int out_size, void* d_ws, size_t ws_size,
                              hipStream_t stream){
  const float* x       = (const float*)d_in[0];
  const float* lnw     = (const float*)d_in[1];
  const float* w_qkv   = (const float*)d_in[2];
  const float* w_out   = (const float*)d_in[3];
  const float* mix_ipa = (const float*)d_in[4];
  const float* mix_daa = (const float*)d_in[5];
  float* out = (float*)d_out;

  // qf 27,262,976 | kf 27,262,976 | vt 33,554,432 | O 33,554,432
  // wqb 221,184 | wob 73,728 | wI 512 | wD 512  => 121,930,752
  if (ws_size < 121930752u) return;

  char* ws = (char*)d_ws;
  unsigned short* qf  = (unsigned short*)(ws + 0);
  unsigned short* kf  = (unsigned short*)(ws + 27262976);
  unsigned short* vt  = (unsigned short*)(ws + 54525952);
  unsigned short* O   = (unsigned short*)(ws + 88080384);
  unsigned short* wqb = (unsigned short*)(ws + 121634816);
  unsigned short* wob = (unsigned short*)(ws + 121856000);
  float* wI = (float*)(ws + 121929728);
  float* wD = (float*)(ws + 121930240);

  k0_prep<<<432, 256, 0, stream>>>(w_qkv, w_out, lnw, mix_ipa, mix_daa, wqb, wob, wI, wD);
  k1_qkv<<<512, 256, 75328, stream>>>(x, wqb, wI, wD, qf, kf, vt);
  k3_attn<<<1024, 256, 34816, stream>>>(qf, kf, vt, O);
  k4_out<<<512, 256, 69632, stream>>>(O, wob, x, out);
}

// Round 14
// 187.146 us; speedup vs baseline: 2.5737x; 1.0005x over previous
//
#include <hip/hip_runtime.h>

#define B_ 4
#define T_ 2048
#define C_ 32
#define H_ 4
#define DQK 416
#define DV 512
#define QSCALE 0.049029033784546f   // 1/sqrt(416)
#define LOG2E 1.4426950408889634f
// kf fragment layout: [bh][kt 64][sf 26][hi 2][key 32][8]
#define KF_BH 851968
#define KF_KT 13312      // shorts per kt tile (26*2*32*8)
// vt fragment layout: [bh][kt 64][dt 16][kh 2][grp 2][qll 32][8tok]
#define VT_KT 16384      // shorts per kt tile

typedef __attribute__((ext_vector_type(8))) short short8;
typedef __attribute__((ext_vector_type(4))) short short4_;
typedef __attribute__((ext_vector_type(4))) float float4_;
typedef __attribute__((ext_vector_type(16))) float f32x16;

// packed nibble tables (blade j -> value), LSB nibble = j0
#define GRADE_PK 0x4333322222211110ULL
#define E0B_PK   0x8077700066600050ULL
#define SRC_PK   0xE0A9800043200000ULL
#define IPOS_PK  0x0700065400032100ULL
#define E0MASK   0xB8E2
#define INVMASK  0x471D
#define QKMASK   0x7F1D
#define BL_PK    0xEAFD98CB43762051ULL

__device__ __forceinline__ float bf2f(unsigned short u){
  union{unsigned int i; float f;} v; v.i = ((unsigned int)u) << 16; return v.f;
}
__device__ __forceinline__ unsigned short f2bf(float f){
  union{float f; unsigned int i;} v; v.f = f;
  unsigned int x = v.i;
  unsigned int r = x + 0x7FFFu + ((x >> 16) & 1u);
  return (unsigned short)(r >> 16);
}
__device__ __forceinline__ unsigned pkbf(float a, float b){
  unsigned ua = __float_as_uint(a) + 0x8000u;
  unsigned ub = __float_as_uint(b) + 0x8000u;
  return __builtin_amdgcn_perm(ub, ua, 0x07060302u);
}

// ---------------- k0: weight prep ----------------
__global__ void k0_prep(const float* __restrict__ w_qkv, const float* __restrict__ w_out,
                        const float* __restrict__ lnw, const float* __restrict__ mix_ipa,
                        const float* __restrict__ mix_daa,
                        unsigned short* __restrict__ wqb, unsigned short* __restrict__ wob,
                        float* __restrict__ wI, float* __restrict__ wD){
  int idx = blockIdx.x * 256 + threadIdx.x;
  if (idx < 9*384*32){
    int i = idx & 31;
    int rest = idx >> 5;
    int o = rest % 384;
    int bb = rest / 384;
    wqb[idx] = f2bf(w_qkv[(o*32 + i)*9 + bb] * lnw[i]);
  }
  if (idx < 9*32*128){
    int i = idx & 127;
    int rest = idx >> 7;
    int o = rest & 31;
    int bb = rest >> 5;
    wob[idx] = f2bf(w_out[(o*128 + i)*9 + bb]);
  }
  if (idx < 128){
    wI[idx] = __expf(mix_ipa[idx]);
    wD[idx] = __expf(mix_daa[idx]);
  }
}

// ---------------- k1: norm + QKV equi-linear + feature build ----------------
// LDS: xJ 20480 | invr 64 | red 512 | ost 4x13568 = 54272  => 75328B (2 blocks/CU)
__global__ __launch_bounds__(256) void k1_qkv(
    const float* __restrict__ x, const unsigned short* __restrict__ wqb,
    const float* __restrict__ wI, const float* __restrict__ wD,
    unsigned short* __restrict__ qf, unsigned short* __restrict__ kf,
    unsigned short* __restrict__ vt){
  extern __shared__ char smem[];
  unsigned short* xJ = (unsigned short*)smem;
  float* invr = (float*)(smem + 20480);
  float* red  = (float*)(smem + 20544);
  unsigned short* ostage = (unsigned short*)(smem + 21056);

  int tid = threadIdx.x;
  int tile = blockIdx.x;
  int b = tile >> 7;
  int t0 = (tile & 127) << 4;

  const float* xt = x + ((size_t)(b*T_ + t0)) * 512;
  #pragma unroll
  for (int pass = 0; pass < 8; ++pass){
    int g = tid + pass*256;
    int t = g >> 7, r = g & 127;
    int ci = r >> 2, j4 = (r & 3) << 2;
    float4_ v = *(const float4_*)(xt + (size_t)t*512 + ci*16 + j4);
    #pragma unroll
    for (int d = 0; d < 4; ++d){
      xJ[((j4 + d)*16 + t)*40 + ci] = f2bf(v[d]);
    }
  }
  __syncthreads();
  if (tid < 128){
    int t = tid >> 3, p = tid & 7;
    int j = (int)((0xEA984320u >> (p*4)) & 15u);
    float s = 0.f;
    #pragma unroll
    for (int i = 0; i < 32; ++i){
      float v = bf2f(xJ[(j*16 + t)*40 + i]);
      s += v*v;
    }
    red[t*8 + p] = s;
  }
  __syncthreads();
  if (tid < 16){
    float s = 0.f;
    #pragma unroll
    for (int p = 0; p < 8; ++p) s += red[tid*8 + p];
    invr[tid] = rsqrtf(s * (1.0f/32.0f) + 1e-5f);
  }
  __syncthreads();

  int wv = tid >> 6, lane = tid & 63, lm = lane & 15, kg = lane >> 4;
  unsigned short* ost = ostage + wv * 6784;   // 16 x 424 shorts
  int h = wv;
  int bh = b * H_ + h;
  unsigned short* vtb = vt + (size_t)bh * 64 * VT_KT;
  const float QSC2 = QSCALE * LOG2E;

  for (int s = 0; s < 3; ++s){
    int c12 = s*4 + h;
    float pr0[2][4], pr1[2][4], pr2[2][4];
    #pragma unroll
    for (int j = 0; j < 16; ++j){
      if (s < 2 && !((QKMASK >> j) & 1)) continue;
      int g  = (int)((GRADE_PK >> (j*4)) & 15);
      bool e0 = (E0MASK >> j) & 1;
      int eb = (int)((E0B_PK >> (j*4)) & 15);
      int sj = (int)((SRC_PK >> (j*4)) & 15);
      #pragma unroll
      for (int nt = 0; nt < 2; ++nt){
        int o = c12*32 + nt*16 + lm;
        float4_ acc = {0.f, 0.f, 0.f, 0.f};
        short8 a0 = *(const short8*)&xJ[(j*16 + lm)*40 + kg*8];
        short8 b0 = *(const short8*)&wqb[((size_t)(g*384 + o))*32 + kg*8];
        acc = __builtin_amdgcn_mfma_f32_16x16x32_bf16(a0, b0, acc, 0, 0, 0);
        if (e0){
          short8 a1 = *(const short8*)&xJ[(sj*16 + lm)*40 + kg*8];
          short8 b1 = *(const short8*)&wqb[((size_t)(eb*384 + o))*32 + kg*8];
          acc = __builtin_amdgcn_mfma_f32_16x16x32_bf16(a1, b1, acc, 0, 0, 0);
        }
        int c = nt*16 + lm;
        if (s == 2){
          // direct store to vt fragment layout (4 tokens contiguous in the 8-slot)
          int dim = c*16 + j;
          short4_ w;
          #pragma unroll
          for (int r = 0; r < 4; ++r) w[r] = (short)f2bf(acc[r] * invr[kg*4 + r]);
          int dt = dim >> 5, qll = dim & 31;
          size_t off = (size_t)(t0 >> 5)*VT_KT + dt*1024 + ((t0 >> 4) & 1)*512
                     + (kg >> 1)*256 + qll*8 + (kg & 1)*4;
          *(short4_*)(vtb + off) = w;
        } else {
          #pragma unroll
          for (int r = 0; r < 4; ++r){
            int t = kg*4 + r;
            float val = acc[r] * invr[t];
            if ((INVMASK >> j) & 1){
              int p = (int)((IPOS_PK >> (j*4)) & 15);
              float f = (s == 0) ? val * wI[h*32 + c] * QSC2 : val;
              ost[t*424 + c*8 + p] = f2bf(f);
            } else {
              float f = (s == 0) ? val * (2.0f * QSC2) * wD[h*32 + c] : val;
              ost[t*424 + 256 + c*5 + (j - 11)] = f2bf(f);
              if (j == 11) pr0[nt][r] = val;
              else if (j == 12) pr1[nt][r] = val;
              else pr2[nt][r] = val;
            }
          }
        }
      }
    }
    if (s < 2){
      // |p|^2 and const slots from registers (lane-local)
      #pragma unroll
      for (int nt = 0; nt < 2; ++nt){
        int c = nt*16 + lm;
        #pragma unroll
        for (int r = 0; r < 4; ++r){
          int t = kg*4 + r;
          float ps = pr0[nt][r]*pr0[nt][r] + pr1[nt][r]*pr1[nt][r] + pr2[nt][r]*pr2[nt][r];
          if (s == 0){
            float wd = wD[h*32 + c] * QSC2;
            ost[t*424 + 256 + c*5 + 3] = f2bf(-ps * wd);
            ost[t*424 + 256 + c*5 + 4] = f2bf(-wd);
          } else {
            ost[t*424 + 256 + c*5 + 3] = f2bf(1.0f);
            ost[t*424 + 256 + c*5 + 4] = f2bf(ps);
          }
        }
      }
      if (s == 0){
        unsigned short* dst = qf + ((size_t)bh*T_ + t0) * DQK;
        for (int ch = lane; ch < 832; ch += 64){
          int t = ch / 52, c8 = ch % 52;
          *(short8*)(dst + (size_t)t*DQK + c8*8) = *(const short8*)&ost[t*424 + c8*8];
        }
      } else {
        unsigned short* dst = kf + (size_t)bh * KF_BH;
        for (int ch = lane; ch < 832; ch += 64){
          int t = ch / 52, c8 = ch % 52;
          int f0 = c8 * 8;
          int hf2 = (f0 >= 208);
          int fl = f0 - hf2*208;
          int s_ = fl >> 4;
          int hi2 = (fl >> 3) & 1;
          int tt = t0 + t;
          size_t off = ((((size_t)(tt >> 5)*26 + hf2*13 + s_)*2 + hi2)*32 + (tt & 31))*8;
          *(short8*)(dst + off) = *(const short8*)&ost[t*424 + c8*8];
        }
      }
    }
  }
}

// ---------------- k3: flash attention — R11 body, P published via LDS ----------
// grid 1024 = [chunk desc 64][bhlo 2][xcd 8], block 256 (4 waves), 2 blocks/CU.
// IDENTICAL to the R11 passing kernel (redundant per-lane softmax for query ql,
// in-register m/l/alpha, defer-max vote, reg-prefetched K, V at iter top, sx via B1)
// EXCEPT: the 16-shfl P pack is replaced by 8 scalar u32 LDS writes into
// Plds[ql][key] (pre-B2), and PV reads P0/P1 as b128 from Plds (post-B2).
// Write keys per lane: crow(r,hi) pairs -> shorts ql*40 + {4hi,8+4hi,16+4hi,24+4hi}(+2).
// Read fragments: P0 = keys hi*8..+7, P1 = keys 16+hi*8..+7 of row ql (same content
// R11's packed registers held).
// LDS: sx 4x32x36 f32 (18432) | Plds 32x40 bf16 (2560) | ostage alias [32][536] => 34304B
__global__ __launch_bounds__(256, 2) void k3_attn(
    const unsigned short* __restrict__ qf, const unsigned short* __restrict__ kf,
    const unsigned short* __restrict__ vt, unsigned short* __restrict__ O){
  extern __shared__ char smem[];
  float* sx = (float*)smem;                               // 4 x 1152 f32
  unsigned short* Plds = (unsigned short*)(smem + 18432); // 32 x 40 shorts
  unsigned short* ostage = (unsigned short*)smem;         // epilogue alias [32][536]

  int tid = threadIdx.x, wv = tid >> 6, lane = tid & 63;
  int ql = lane & 31, hi = lane >> 5;
  int blk = blockIdx.x;
  int bh = 2*(blk & 7) + ((blk >> 3) & 1);
  int chunk = 63 - (blk >> 4);
  int q0 = chunk * 32;

  const unsigned short* qfb = qf + (size_t)bh * T_ * DQK;
  const unsigned short* vtb = vt + (size_t)bh * 64 * VT_KT;
  unsigned short* Ob = O + (size_t)bh * T_ * DV;

  int FS = (wv < 2) ? wv*7 : 14 + (wv - 2)*6;     // sf base
  int FB = (wv < 2) ? wv*112 : 224 + (wv - 2)*96; // feature base
  const unsigned short* kfw = kf + (size_t)bh * KF_BH + (size_t)FS*512 + hi*256 + ql*8;

  // Q fragments (6 or 7 per wave)
  short8 qfr[7];
  {
    const unsigned short* qrow = qfb + (size_t)(q0 + ql)*DQK + FB + hi*8;
    #pragma unroll
    for (int s_ = 0; s_ < 6; ++s_) qfr[s_] = *(const short8*)(qrow + s_*16);
    if (wv < 2) qfr[6] = *(const short8*)(qrow + 96);
  }

  f32x16 acc[4];
  #pragma unroll
  for (int i = 0; i < 4; ++i){
    #pragma unroll
    for (int j = 0; j < 16; ++j) acc[i][j] = 0.f;
  }
  float m = -1e30f, l = 0.f;

  // prologue: K(0) -> kc
  short8 kc[7];
  {
    #pragma unroll
    for (int i = 0; i < 6; ++i) kc[i] = *(const short8*)(kfw + i*512);
    if (wv < 2) kc[6] = *(const short8*)(kfw + 3072);
  }

  for (int kt = 0; kt <= chunk; ++kt){
    // V fragment loads: issue early, consumed at PV (after B2)
    short8 vf[8];
    {
      const unsigned short* vk = vtb + (size_t)kt*VT_KT + (wv*4)*1024 + lane*8;
      #pragma unroll
      for (int dti = 0; dti < 4; ++dti){
        vf[dti*2]     = *(const short8*)(vk + dti*1024);
        vf[dti*2 + 1] = *(const short8*)(vk + dti*1024 + 512);
      }
    }
    // QK quarter from registers
    f32x16 S;
    #pragma unroll
    for (int j = 0; j < 16; ++j) S[j] = 0.f;
    __builtin_amdgcn_s_setprio(1);
    #pragma unroll
    for (int s_ = 0; s_ < 6; ++s_)
      S = __builtin_amdgcn_mfma_f32_32x32x16_bf16(kc[s_], qfr[s_], S, 0, 0, 0);
    if (wv < 2)
      S = __builtin_amdgcn_mfma_f32_32x32x16_bf16(kc[6], qfr[6], S, 0, 0, 0);
    __builtin_amdgcn_s_setprio(0);
    // write own quarter-scores
    {
      float* sxw = sx + wv*1152 + ql*36;
      #pragma unroll
      for (int g = 0; g < 4; ++g){
        float4_ w4;
        #pragma unroll
        for (int u = 0; u < 4; ++u) w4[u] = S[g*4 + u];
        *(float4_*)(sxw + g*8 + hi*4) = w4;
      }
    }
    __syncthreads();   // B1: quarters exchanged
    // merge 3 partners (redundant per lane, query ql — R11 path)
    float s_[16];
    {
      int w1 = (wv + 1) & 3, w2 = (wv + 2) & 3, w3 = (wv + 3) & 3;
      #pragma unroll
      for (int g = 0; g < 4; ++g){
        float4_ a1 = *(const float4_*)(sx + w1*1152 + ql*36 + g*8 + hi*4);
        float4_ a2 = *(const float4_*)(sx + w2*1152 + ql*36 + g*8 + hi*4);
        float4_ a3 = *(const float4_*)(sx + w3*1152 + ql*36 + g*8 + hi*4);
        #pragma unroll
        for (int u = 0; u < 4; ++u) s_[g*4 + u] = S[g*4 + u] + a1[u] + a2[u] + a3[u];
      }
    }
    // prefetch K(kt+1) into kn
    short8 kn[7];
    if (kt < chunk){
      const unsigned short* kk = kfw + (size_t)(kt + 1)*KF_KT;
      #pragma unroll
      for (int i = 0; i < 6; ++i) kn[i] = *(const short8*)(kk + i*512);
      if (wv < 2) kn[6] = *(const short8*)(kk + 3072);
    }
    // causal mask (diagonal tile)
    if (kt == chunk){
      #pragma unroll
      for (int r = 0; r < 16; ++r){
        int kr = (r & 3) + 8*(r >> 2) + 4*hi;
        if (kr > ql) s_[r] = -1e30f;
      }
    }
    // online softmax in exp2 domain (R11 path, in-register m/l)
    float mx0 = fmaxf(fmaxf(s_[0], s_[1]), s_[2]);
    float mx1 = fmaxf(fmaxf(s_[3], s_[4]), s_[5]);
    float mx2 = fmaxf(fmaxf(s_[6], s_[7]), s_[8]);
    float mx3 = fmaxf(fmaxf(s_[9], s_[10]), s_[11]);
    float mx4 = fmaxf(fmaxf(s_[12], s_[13]), s_[14]);
    float pmax = fmaxf(fmaxf(fmaxf(mx0, mx1), fmaxf(mx2, mx3)), fmaxf(mx4, s_[15]));
    pmax = fmaxf(pmax, __shfl_xor(pmax, 32));
    if (!__all(pmax <= m + 11.54f)){
      float mn = fmaxf(m, pmax);
      float al = __builtin_amdgcn_exp2f(m - mn);
      m = mn; l *= al;
      #pragma unroll
      for (int dt = 0; dt < 4; ++dt) acc[dt] *= al;
    }
    float p[16]; float rs = 0.f;
    #pragma unroll
    for (int r = 0; r < 16; ++r){ p[r] = __builtin_amdgcn_exp2f(s_[r] - m); rs += p[r]; }
    rs += __shfl_xor(rs, 32);
    l += rs;
    // publish P row: this lane owns keys crow(r,hi)=(r&3)+8*(r>>2)+4*hi (adjacent pairs)
    {
      unsigned* Pw0 = (unsigned*)(Plds + ql*40 + hi*4);
      Pw0[0] = pkbf(p[0], p[1]);
      Pw0[1] = pkbf(p[2], p[3]);
      unsigned* Pw1 = (unsigned*)(Plds + ql*40 + 8 + hi*4);
      Pw1[0] = pkbf(p[4], p[5]);
      Pw1[1] = pkbf(p[6], p[7]);
      unsigned* Pw2 = (unsigned*)(Plds + ql*40 + 16 + hi*4);
      Pw2[0] = pkbf(p[8], p[9]);
      Pw2[1] = pkbf(p[10], p[11]);
      unsigned* Pw3 = (unsigned*)(Plds + ql*40 + 24 + hi*4);
      Pw3[0] = pkbf(p[12], p[13]);
      Pw3[1] = pkbf(p[14], p[15]);
    }
    __syncthreads();   // B2: P published; sx reads done (next iter's sx write safe)
    // P fragments from LDS: keys hi*8..+7 (P0), 16+hi*8..+7 (P1) of row ql
    short8 P0 = *(const short8*)(Plds + ql*40 + hi*8);
    short8 P1 = *(const short8*)(Plds + ql*40 + 16 + hi*8);
    // PV: own 128-dim quarter
    __builtin_amdgcn_s_setprio(1);
    #pragma unroll
    for (int dti = 0; dti < 4; ++dti){
      acc[dti] = __builtin_amdgcn_mfma_f32_32x32x16_bf16(vf[dti*2],     P0, acc[dti], 0, 0, 0);
      acc[dti] = __builtin_amdgcn_mfma_f32_32x32x16_bf16(vf[dti*2 + 1], P1, acc[dti], 0, 0, 0);
    }
    __builtin_amdgcn_s_setprio(0);
    // rotate prefetched K into place (register-only)
    if (kt < chunk){
      #pragma unroll
      for (int i = 0; i < 6; ++i) kc[i] = kn[i];
      if (wv < 2) kc[6] = kn[6];
    }
  }

  __syncthreads();   // all loop LDS reads done before ostage alias writes
  // ---- epilogue: normalize (in-register l), transpose via LDS, coalesced store ----
  float il = 1.0f / l;
  #pragma unroll
  for (int dti = 0; dti < 4; ++dti){
    #pragma unroll
    for (int g = 0; g < 4; ++g){
      short4_ w;
      #pragma unroll
      for (int u = 0; u < 4; ++u) w[u] = (short)f2bf(acc[dti][g*4 + u] * il);
      *(short4_*)&ostage[ql*536 + wv*128 + dti*32 + g*8 + hi*4] = w;
    }
  }
  __syncthreads();
  {
    int row = tid >> 3, c8b = tid & 7;
    #pragma unroll
    for (int i = 0; i < 8; ++i){
      int c8 = c8b + i*8;
      *(short8*)(Ob + (size_t)(q0 + row)*DV + c8*8) = *(const short8*)&ostage[row*536 + c8*8];
    }
  }
}

// ---------------- k4: out equi-linear + residual ----------------
// LDS: oT 69632B; fst (32768B) ALIASES oT after all MFMA reads complete. 2 blocks/CU.
__global__ __launch_bounds__(256) void k4_out(
    const unsigned short* __restrict__ O, const unsigned short* __restrict__ wob,
    const float* __restrict__ x, float* __restrict__ out){
  extern __shared__ char smem[];
  unsigned short* oT = (unsigned short*)smem;
  float* fst = (float*)smem;   // alias (used after barrier)

  int tid = threadIdx.x, wv = tid >> 6, lane = tid & 63, lm = lane & 15, kg = lane >> 4;
  int blk = blockIdx.x;
  int b = blk >> 7, t0 = (blk & 127) << 4;

  for (int ch = tid; ch < 4096; ch += 256){
    int hh = ch >> 10, t = (ch >> 6) & 15, c8 = ch & 63;
    short8 v = *(const short8*)(O + ((size_t)(b*H_ + hh)*T_ + (t0 + t))*512 + c8*8);
    int c = c8 >> 1, j0 = (c8 & 1)*8;
    int ci = hh*32 + c;
    #pragma unroll
    for (int d = 0; d < 8; ++d)
      oT[((j0 + d)*16 + t)*136 + ci] = (unsigned short)v[d];
  }
  __syncthreads();

  float accv[4][2][4];
  #pragma unroll
  for (int bi = 0; bi < 4; ++bi){
    int j  = (int)((BL_PK >> ((wv*4 + bi)*4)) & 15);
    int g  = (int)((GRADE_PK >> (j*4)) & 15);
    bool e0 = (E0MASK >> j) & 1;
    int eb = (int)((E0B_PK >> (j*4)) & 15);
    int sj = (int)((SRC_PK >> (j*4)) & 15);
    #pragma unroll
    for (int nt = 0; nt < 2; ++nt){
      int o = nt*16 + lm;
      float4_ acc = {0.f, 0.f, 0.f, 0.f};
      #pragma unroll
      for (int ks = 0; ks < 4; ++ks){
        short8 a = *(const short8*)&oT[(j*16 + lm)*136 + ks*32 + kg*8];
        short8 bfr = *(const short8*)(wob + ((size_t)(g*32 + o))*128 + ks*32 + kg*8);
        acc = __builtin_amdgcn_mfma_f32_16x16x32_bf16(a, bfr, acc, 0, 0, 0);
      }
      if (e0){
        #pragma unroll
        for (int ks = 0; ks < 4; ++ks){
          short8 a = *(const short8*)&oT[(sj*16 + lm)*136 + ks*32 + kg*8];
          short8 bfr = *(const short8*)(wob + ((size_t)(eb*32 + o))*128 + ks*32 + kg*8);
          acc = __builtin_amdgcn_mfma_f32_16x16x32_bf16(a, bfr, acc, 0, 0, 0);
        }
      }
      #pragma unroll
      for (int r = 0; r < 4; ++r) accv[bi][nt][r] = acc[r];
    }
  }
  __syncthreads();   // all oT reads done -> fst may overwrite
  #pragma unroll
  for (int bi = 0; bi < 4; ++bi){
    int j = (int)((BL_PK >> ((wv*4 + bi)*4)) & 15);
    #pragma unroll
    for (int nt = 0; nt < 2; ++nt){
      int o = nt*16 + lm;
      #pragma unroll
      for (int r = 0; r < 4; ++r){
        int t = kg*4 + r;
        fst[t*512 + o*16 + j] = accv[bi][nt][r];
      }
    }
  }
  __syncthreads();
  const float* xb = x + ((size_t)(b*T_ + t0))*512;
  float* ob = out + ((size_t)(b*T_ + t0))*512;
  for (int ch = tid; ch < 2048; ch += 256){
    float4_ v  = *(const float4_*)(fst + (size_t)ch*4);
    float4_ xv = *(const float4_*)(xb + (size_t)ch*4);
    *(float4_*)(ob + (size_t)ch*4) = v + xv;
  }
}

// ---------------- launcher ----------------
extern "C" void kernel_launch(void* const* d_in, const int* in_sizes, int n_in,
                              void* d_out, int out_size, void* d_ws, size_t ws_size,
                              hipStream_t stream){
  const float* x       = (const float*)d_in[0];
  const float* lnw     = (const float*)d_in[1];
  const float* w_qkv   = (const float*)d_in[2];
  const float* w_out   = (const float*)d_in[3];
  const float* mix_ipa = (const float*)d_in[4];
  const float* mix_daa = (const float*)d_in[5];
  float* out = (float*)d_out;

  // qf 27,262,976 | kf 27,262,976 | vt 33,554,432 | O 33,554,432
  // wqb 221,184 | wob 73,728 | wI 512 | wD 512  => 121,930,752
  if (ws_size < 121930752u) return;

  char* ws = (char*)d_ws;
  unsigned short* qf  = (unsigned short*)(ws + 0);
  unsigned short* kf  = (unsigned short*)(ws + 27262976);
  unsigned short* vt  = (unsigned short*)(ws + 54525952);
  unsigned short* O   = (unsigned short*)(ws + 88080384);
  unsigned short* wqb = (unsigned short*)(ws + 121634816);
  unsigned short* wob = (unsigned short*)(ws + 121856000);
  float* wI = (float*)(ws + 121929728);
  float* wD = (float*)(ws + 121930240);

  k0_prep<<<432, 256, 0, stream>>>(w_qkv, w_out, lnw, mix_ipa, mix_daa, wqb, wob, wI, wD);
  k1_qkv<<<512, 256, 75328, stream>>>(x, wqb, wI, wD, qf, kf, vt);
  k3_attn<<<1024, 256, 34304, stream>>>(qf, kf, vt, O);
  k4_out<<<512, 256, 69632, stream>>>(O, wob, x, out);
}